// Round 1
// baseline (1399.324 us; speedup 1.0000x reference)
//
#include <hip/hip_runtime.h>
#include <math.h>

// Problem dims
#define Bq 4
#define Tq 64
#define Nq 256
#define Eq 128
#define Dq 64
#define Rq (Bq*Nq*Tq)      // 65536 rows (b,n,t)
#define ELEMS (Rq*Dq)      // 4194304

// ws offsets (in floats)
#define O_Q    0
#define O_K    65536
#define O_HD   73728
#define O_IDD  204800
#define O_IBD  205824
#define O_HG   206336
#define O_IDG  239104
#define O_IBG  239360
#define O_AN   239488
#define O_AG   501632
#define O_WFT  567168
#define O_WGT  575360
#define O_WOT  583552
#define O_WET  591744
#define O_FTT  595840
#define O_GTT  608128
#define O_STT  620416
#define O_BIG  632704
#define WS_FLOATS (O_BIG + 6*ELEMS)

__device__ __forceinline__ float sigmoidf_(float x){ return 1.f/(1.f+expf(-x)); }

// ---------------- weight transposes (once per launch) ----------------
// dst[c*64 + r] = src[r*cols + c]   (rows always 64)
__global__ __launch_bounds__(256) void k_tw(
    const float* __restrict__ Wfuse, const float* __restrict__ Wgfuse,
    const float* __restrict__ outW,  const float* __restrict__ endW,
    const float* __restrict__ filtW, const float* __restrict__ gateW,
    const float* __restrict__ skipW, float* __restrict__ ws) {
  int job = blockIdx.x;
  const float* src; float* dst; int cols;
  if      (job==0){ src=Wfuse;  dst=ws+O_WFT; cols=128; }
  else if (job==1){ src=Wgfuse; dst=ws+O_WGT; cols=128; }
  else if (job==2){ src=outW;   dst=ws+O_WOT; cols=128; }
  else if (job==3){ src=endW;   dst=ws+O_WET; cols=64; }
  else if (job<7) { int i=job-4;  src=filtW+i*4096; dst=ws+O_FTT+i*4096; cols=64; }
  else if (job<10){ int i=job-7;  src=gateW+i*4096; dst=ws+O_GTT+i*4096; cols=64; }
  else            { int i=job-10; src=skipW+i*4096; dst=ws+O_STT+i*4096; cols=64; }
  int nelem = 64*cols;
  for (int idx=threadIdx.x; idx<nelem; idx+=256){
    int r = idx / cols, c = idx % cols;
    dst[c*64 + r] = src[idx];
  }
}

// ---------------- phase 0: hypergraph construction ----------------
__global__ __launch_bounds__(64) void k_q(const float* __restrict__ X,
    const float* __restrict__ nodeW, const float* __restrict__ nodeB,
    const float* __restrict__ Wq, float* __restrict__ Q) {
  int bn = blockIdx.x; int b = bn >> 8; int n = bn & 255;
  int tid = threadIdx.x;
  __shared__ float xcol[Tq];
  __shared__ float ee[Dq];
  xcol[tid] = X[(b*Tq + tid)*Nq + n];
  __syncthreads();
  float acc = 0.f;
  #pragma unroll 8
  for (int t=0;t<Tq;t++) acc += xcol[t]*nodeW[tid*Tq+t];
  ee[tid] = acc + nodeB[tid];
  __syncthreads();
  float q = 0.f;
  #pragma unroll 8
  for (int d=0; d<Dq; d++) q += ee[d]*Wq[tid*Dq+d];
  Q[bn*Dq+tid] = q;
}

__global__ __launch_bounds__(64) void k_k(const float* __restrict__ he,
    const float* __restrict__ Wk, float* __restrict__ K) {
  int e = blockIdx.x; int tid = threadIdx.x;
  __shared__ float hr[Dq];
  hr[tid] = he[e*Dq+tid];
  __syncthreads();
  float acc = 0.f;
  #pragma unroll 8
  for (int d=0; d<Dq; d++) acc += hr[d]*Wk[tid*Dq+d];
  K[e*Dq+tid] = acc;
}

__global__ __launch_bounds__(128) void k_h(const float* __restrict__ Q,
    const float* __restrict__ K, float* __restrict__ H, float* __restrict__ invDd) {
  int bn = blockIdx.x; int tid = threadIdx.x;
  __shared__ float qr[Dq];
  __shared__ float red[Eq];
  if (tid < Dq) qr[tid] = Q[bn*Dq+tid];
  __syncthreads();
  float s = 0.f;
  const float* kr = K + tid*Dq;
  #pragma unroll 8
  for (int d=0; d<Dq; d++) s += qr[d]*kr[d];
  s *= 0.125f;   // 1/sqrt(64)
  red[tid] = s; __syncthreads();
  for (int off=64; off>0; off>>=1){ if (tid<off) red[tid]=fmaxf(red[tid],red[tid+off]); __syncthreads(); }
  float mx = red[0]; __syncthreads();
  float e = expf(s-mx);
  red[tid] = e; __syncthreads();
  for (int off=64; off>0; off>>=1){ if (tid<off) red[tid]+=red[tid+off]; __syncthreads(); }
  float sm = red[0]; __syncthreads();
  float h = e/sm;
  H[bn*Eq+tid] = h;
  red[tid]=h; __syncthreads();
  for (int off=64; off>0; off>>=1){ if (tid<off) red[tid]+=red[tid+off]; __syncthreads(); }
  if (tid==0){ float dd = red[0]; invDd[bn] = dd>0.f ? 1.f/(dd+1e-8f) : 0.f; }
}

__global__ __launch_bounds__(256) void k_bd(const float* __restrict__ H,
    float* __restrict__ invBd) {
  int idx = blockIdx.x*256 + threadIdx.x;
  if (idx >= Bq*Eq) return;
  int b = idx >> 7; int e = idx & 127;
  float s=0.f;
  for (int n=0;n<Nq;n++) s += H[(b*Nq+n)*Eq + e];
  invBd[idx] = s>0.f ? 1.f/(s+1e-8f) : 0.f;
}

__global__ __launch_bounds__(128) void k_hgeo(const float* __restrict__ A,
    const float* __restrict__ Gl, float* __restrict__ Hg, float* __restrict__ invDg) {
  int n = blockIdx.x; int tid = threadIdx.x;
  __shared__ float ar[Nq];
  __shared__ float red[Eq];
  ar[tid] = A[n*Nq+tid]; ar[tid+128] = A[n*Nq+128+tid];
  __syncthreads();
  float s=0.f;
  #pragma unroll 4
  for (int k=0;k<Nq;k++) s += ar[k]*Gl[k*Eq+tid];
  Hg[n*Eq+tid] = s;
  red[tid]=s; __syncthreads();
  for (int off=64; off>0; off>>=1){ if (tid<off) red[tid]+=red[tid+off]; __syncthreads(); }
  if (tid==0){ float dg=red[0]; invDg[n] = dg>0.f ? 1.f/(dg+1e-8f):0.f; }
}

__global__ __launch_bounds__(128) void k_bg(const float* __restrict__ Hg,
    float* __restrict__ invBg){
  int e = threadIdx.x;
  float s=0.f;
  for (int n=0;n<Nq;n++) s += Hg[n*Eq+e];
  invBg[e] = s>0.f ? 1.f/(s+1e-8f) : 0.f;
}

__global__ __launch_bounds__(256) void k_anorm(const float* __restrict__ H,
    const float* __restrict__ invDd, const float* __restrict__ invBd,
    float* __restrict__ An) {
  int bid = blockIdx.x; int b = bid>>8; int i = bid&255; int j = threadIdx.x;
  __shared__ float hr[Eq];
  if (j < Eq) hr[j] = H[(b*Nq+i)*Eq+j] * invBd[b*Eq+j];
  __syncthreads();
  const float* hj = H + (b*Nq+j)*Eq;
  float s=0.f;
  #pragma unroll 8
  for (int e=0;e<Eq;e++) s += hr[e]*hj[e];
  An[(b*Nq+i)*Nq + j] = invDd[b*Nq+i]*s;
}

__global__ __launch_bounds__(256) void k_ageo(const float* __restrict__ Hg,
    const float* __restrict__ invDg, const float* __restrict__ invBg,
    float* __restrict__ Ag) {
  int i = blockIdx.x; int j = threadIdx.x;
  __shared__ float hr[Eq];
  if (j<Eq) hr[j] = Hg[i*Eq+j]*invBg[j];
  __syncthreads();
  const float* hj = Hg + j*Eq;
  float s=0.f;
  #pragma unroll 8
  for (int e=0;e<Eq;e++) s+=hr[e]*hj[e];
  Ag[i*Nq+j] = invDg[i]*s;
}

// ---------------- start: x = X*start_W + start_b ; skip = x ----------------
// big-tensor layout: [B, N, T, D]  (row index r=(b*N+n)*T+t, D contiguous)
__global__ __launch_bounds__(256) void k_start(const float* __restrict__ X,
    const float* __restrict__ sW, const float* __restrict__ sB,
    float* __restrict__ x, float* __restrict__ skip) {
  int idx4 = blockIdx.x*256+threadIdx.x;
  int base = idx4*4;
  int row = base>>6, d0 = base&63;
  int b = row>>14, n = (row>>6)&255, t = row&63;
  float xv = X[(b*Tq+t)*Nq + n];
  float4 w = *(const float4*)&sW[d0];
  float4 bb = *(const float4*)&sB[d0];
  float4 v = make_float4(xv*w.x+bb.x, xv*w.y+bb.y, xv*w.z+bb.z, xv*w.w+bb.w);
  *(float4*)&x[base] = v;
  *(float4*)&skip[base] = v;
}

// ---------------- filter*gate + skip update (fused) ----------------
__global__ __launch_bounds__(256) void k_fg(
    const float* __restrict__ x, const float* __restrict__ ftT,
    const float* __restrict__ gtT, const float* __restrict__ stT,
    const float* __restrict__ fb, const float* __restrict__ gb,
    const float* __restrict__ sb, float* __restrict__ xf,
    float* __restrict__ skip) {
  __shared__ float wf[4096], wg[4096], wsk[4096];
  __shared__ float xsr[16*68], xfs[16*68];
  int tid = threadIdx.x;
  for (int i=tid;i<4096;i+=256){ wf[i]=ftT[i]; wg[i]=gtT[i]; wsk[i]=stT[i]; }
  int row0 = blockIdx.x*16;
  {
    int r = tid>>4, c4=(tid&15)*4;
    *(float4*)&xsr[r*68+c4] = *(const float4*)&x[(row0+r)*64+c4];
  }
  __syncthreads();
  int dp = tid&63, rg = tid>>6;  // 4 waves, 4 rows each
  float accf[4] = {0,0,0,0}, accg[4] = {0,0,0,0};
  float fbv = fb[dp], gbv = gb[dp];
  #pragma unroll 4
  for (int k=0;k<64;k++){
    float wfv = wf[k*64+dp], wgv = wg[k*64+dp];
    #pragma unroll
    for (int rr=0;rr<4;rr++){
      float v = xsr[(rg*4+rr)*68+k];
      accf[rr] += v*wfv; accg[rr] += v*wgv;
    }
  }
  #pragma unroll
  for (int rr=0;rr<4;rr++){
    float val = tanhf(accf[rr]+fbv) * sigmoidf_(accg[rr]+gbv);
    xf[(row0+rg*4+rr)*64+dp] = val;
    xfs[(rg*4+rr)*68+dp] = val;
  }
  __syncthreads();
  float sbv = sb[dp];
  float accs[4] = {0,0,0,0};
  #pragma unroll 4
  for (int k=0;k<64;k++){
    float wsv = wsk[k*64+dp];
    #pragma unroll
    for (int rr=0;rr<4;rr++) accs[rr] += xfs[(rg*4+rr)*68+k]*wsv;
  }
  #pragma unroll
  for (int rr=0;rr<4;rr++){
    int r = row0+rg*4+rr;
    skip[r*64+dp] += accs[rr]+sbv;
  }
}

// ---------------- spatial: out = (Adj ⊗ in) @ Wc ----------------
// per b: Adj[256,256] @ in[b] viewed as [256(n), 4096(t*64+d)], then per-t D×D conv.
// block: 32 m-rows × 128 cols (2 t). grid = b(4) × mc(8) × cc(32) = 1024
__global__ __launch_bounds__(256) void k_spatial(const float* __restrict__ Adj,
    int adjStride, const float* __restrict__ in, const float* __restrict__ Wc,
    float* __restrict__ out) {
  int bid = blockIdx.x;
  int cc = bid & 31; int mc = (bid>>5)&7; int b = bid>>8;
  int m0 = mc*32; int t0 = cc*2;
  const float* A = Adj + (size_t)b*adjStride;
  __shared__ float adj_s[32*64];
  __shared__ float xs[64*128];       // reused as tmp[32*128] in phase 2
  __shared__ float wcv[64*64];
  for (int i=threadIdx.x; i<4096; i+=256) wcv[i] = Wc[i];
  int cg = threadIdx.x & 31; int mg = threadIdx.x >> 5;   // 8 m-groups of 4
  int c0l = cg*4;
  float acc[4][4] = {};
  for (int nc=0; nc<4; ++nc) {
    __syncthreads();
    { // stage adj 32x64
      int base = threadIdx.x*8;
      int r = base>>6, c = base&63;
      *(float4*)&adj_s[r*64+c]   = *(const float4*)&A[(m0+r)*Nq + nc*64 + c];
      *(float4*)&adj_s[r*64+c+4] = *(const float4*)&A[(m0+r)*Nq + nc*64 + c + 4];
    }
    { // stage xs 64x128 (contiguous 128 floats per n)
      int r = threadIdx.x>>2, q = threadIdx.x&3;
      const float4* src = (const float4*)(in + ((size_t)(b*Nq + nc*64 + r)*Tq + t0)*64 + q*32);
      float4* dst = (float4*)&xs[r*128 + q*32];
      #pragma unroll
      for (int u=0;u<8;u++) dst[u] = src[u];
    }
    __syncthreads();
    #pragma unroll 2
    for (int nn=0; nn<64; ++nn) {
      float4 xv = *(float4*)&xs[nn*128 + c0l];
      #pragma unroll
      for (int mi=0; mi<4; ++mi) {
        float a = adj_s[(mg*4+mi)*64 + nn];
        acc[mi][0] += a*xv.x; acc[mi][1] += a*xv.y;
        acc[mi][2] += a*xv.z; acc[mi][3] += a*xv.w;
      }
    }
  }
  __syncthreads();
  #pragma unroll
  for (int mi=0;mi<4;mi++)
    *(float4*)&xs[(mg*4+mi)*128 + c0l] =
      make_float4(acc[mi][0],acc[mi][1],acc[mi][2],acc[mi][3]);
  __syncthreads();
  int tloc = c0l>>6; int dp0 = c0l&63;
  float acc2[4][4] = {};
  #pragma unroll 2
  for (int d=0; d<64; ++d) {
    float4 wv = *(float4*)&wcv[d*64+dp0];
    #pragma unroll
    for (int mi=0;mi<4;mi++) {
      float tv = xs[(mg*4+mi)*128 + tloc*64 + d];
      acc2[mi][0] += tv*wv.x; acc2[mi][1] += tv*wv.y;
      acc2[mi][2] += tv*wv.z; acc2[mi][3] += tv*wv.w;
    }
  }
  #pragma unroll
  for (int mi=0;mi<4;mi++){
    size_t o = ((size_t)(b*Nq + m0 + mg*4+mi)*Tq + t0 + tloc)*64 + dp0;
    *(float4*)&out[o] = make_float4(acc2[mi][0],acc2[mi][1],acc2[mi][2],acc2[mi][3]);
  }
}

// ---------------- combine: xd <- V*xd + (1-V)*xg ----------------
// V = sigmoid(xd·WfA + xg·WgA + x·(WfB+WgB)) per (row, col)
__global__ __launch_bounds__(256) void k_combine(float* __restrict__ xd,
    const float* __restrict__ xg, const float* __restrict__ x,
    const float* __restrict__ wfT, const float* __restrict__ wgT) {
  __shared__ float xds[16*68], xgs[16*68], xss[16*68];
  __shared__ float wa[4096], wb[4096];
  int tid = threadIdx.x; int row0 = blockIdx.x*16;
  { int r=tid>>4, c4=(tid&15)*4;
    *(float4*)&xds[r*68+c4] = *(const float4*)&xd[(row0+r)*64+c4];
    *(float4*)&xgs[r*68+c4] = *(const float4*)&xg[(row0+r)*64+c4];
    *(float4*)&xss[r*68+c4] = *(const float4*)&x[(row0+r)*64+c4]; }
  for (int i=tid;i<4096;i+=256){ wa[i]=wfT[i]; wb[i]=wgT[i]; }
  __syncthreads();
  int rg=tid>>4; int dp0=(tid&15)*4;
  float4 acc = make_float4(0.f,0.f,0.f,0.f);
  #pragma unroll 4
  for (int k=0;k<64;k++){
    float4 wfa = *(const float4*)&wa[k*64+dp0];
    float4 wga = *(const float4*)&wb[k*64+dp0];
    float xdk = xds[rg*68+k], xgk = xgs[rg*68+k];
    acc.x += xdk*wfa.x + xgk*wga.x;
    acc.y += xdk*wfa.y + xgk*wga.y;
    acc.z += xdk*wfa.z + xgk*wga.z;
    acc.w += xdk*wfa.w + xgk*wga.w;
  }
  __syncthreads();
  for (int i=tid;i<4096;i+=256){ wa[i]=wfT[4096+i]+wgT[4096+i]; }
  __syncthreads();
  #pragma unroll 4
  for (int k=0;k<64;k++){
    float4 wv = *(const float4*)&wa[k*64+dp0];
    float xk = xss[rg*68+k];
    acc.x += xk*wv.x; acc.y += xk*wv.y; acc.z += xk*wv.z; acc.w += xk*wv.w;
  }
  float4 V = make_float4(sigmoidf_(acc.x), sigmoidf_(acc.y),
                         sigmoidf_(acc.z), sigmoidf_(acc.w));
  float4 xdv = *(float4*)&xds[rg*68+dp0];
  float4 xgv = *(float4*)&xgs[rg*68+dp0];
  float4 o = make_float4(V.x*xdv.x+(1.f-V.x)*xgv.x,
                         V.y*xdv.y+(1.f-V.y)*xgv.y,
                         V.z*xdv.z+(1.f-V.z)*xgv.z,
                         V.w*xdv.w+(1.f-V.w)*xgv.w);
  *(float4*)&xd[(row0+rg)*64+dp0] = o;
}

// ---------------- out-proj + layernorm ----------------
__global__ __launch_bounds__(256) void k_out(const float* __restrict__ o0,
    const float* __restrict__ o1, const float* __restrict__ woT,
    const float* __restrict__ ob, const float* __restrict__ gamma,
    const float* __restrict__ beta, float* __restrict__ xn) {
  __shared__ float s0[16*68], s1[16*68];
  __shared__ float w[4096];
  int tid=threadIdx.x; int row0=blockIdx.x*16;
  { int r=tid>>4, c4=(tid&15)*4;
    *(float4*)&s0[r*68+c4] = *(const float4*)&o0[(row0+r)*64+c4];
    *(float4*)&s1[r*68+c4] = *(const float4*)&o1[(row0+r)*64+c4]; }
  for (int i=tid;i<4096;i+=256) w[i]=woT[i];
  __syncthreads();
  int rg=tid>>4, dp0=(tid&15)*4;
  float4 acc=make_float4(0.f,0.f,0.f,0.f);
  #pragma unroll 4
  for (int k=0;k<64;k++){
    float4 wv=*(const float4*)&w[k*64+dp0];
    float v=s0[rg*68+k];
    acc.x+=v*wv.x; acc.y+=v*wv.y; acc.z+=v*wv.z; acc.w+=v*wv.w;
  }
  __syncthreads();
  for (int i=tid;i<4096;i+=256) w[i]=woT[4096+i];
  __syncthreads();
  #pragma unroll 4
  for (int k=0;k<64;k++){
    float4 wv=*(const float4*)&w[k*64+dp0];
    float v=s1[rg*68+k];
    acc.x+=v*wv.x; acc.y+=v*wv.y; acc.z+=v*wv.z; acc.w+=v*wv.w;
  }
  float4 b4=*(const float4*)&ob[dp0];
  float y0=acc.x+b4.x, y1=acc.y+b4.y, y2=acc.z+b4.z, y3=acc.w+b4.w;
  float s = y0+y1+y2+y3;
  s += __shfl_xor(s,1); s += __shfl_xor(s,2); s += __shfl_xor(s,4); s += __shfl_xor(s,8);
  float mean = s*(1.f/64.f);
  float e0=y0-mean, e1=y1-mean, e2=y2-mean, e3=y3-mean;
  float sq = e0*e0+e1*e1+e2*e2+e3*e3;
  sq += __shfl_xor(sq,1); sq += __shfl_xor(sq,2); sq += __shfl_xor(sq,4); sq += __shfl_xor(sq,8);
  float rstd = rsqrtf(sq*(1.f/64.f)+1e-5f);
  float4 g4=*(const float4*)&gamma[dp0], be4=*(const float4*)&beta[dp0];
  float4 o = make_float4(e0*rstd*g4.x+be4.x, e1*rstd*g4.y+be4.y,
                         e2*rstd*g4.z+be4.z, e3*rstd*g4.w+be4.w);
  *(float4*)&xn[(row0+rg)*64+dp0]=o;
}

// ---------------- end: out = relu(skip) @ end_W.T + end_b, transposed to [B,T,N,D]
__global__ __launch_bounds__(256) void k_end(const float* __restrict__ skip,
    const float* __restrict__ weT, const float* __restrict__ eb,
    float* __restrict__ out) {
  __shared__ float ss[16*68];
  __shared__ float w[4096];
  int tid=threadIdx.x; int row0=blockIdx.x*16;
  { int r=tid>>4, c4=(tid&15)*4;
    float4 v = *(const float4*)&skip[(row0+r)*64+c4];
    v.x=fmaxf(v.x,0.f); v.y=fmaxf(v.y,0.f); v.z=fmaxf(v.z,0.f); v.w=fmaxf(v.w,0.f);
    *(float4*)&ss[r*68+c4] = v; }
  for (int i=tid;i<4096;i+=256) w[i]=weT[i];
  __syncthreads();
  int rg=tid>>4, dp0=(tid&15)*4;
  float4 acc=make_float4(0.f,0.f,0.f,0.f);
  #pragma unroll 4
  for (int k=0;k<64;k++){
    float4 wv=*(const float4*)&w[k*64+dp0];
    float v=ss[rg*68+k];
    acc.x+=v*wv.x; acc.y+=v*wv.y; acc.z+=v*wv.z; acc.w+=v*wv.w;
  }
  float4 b4=*(const float4*)&eb[dp0];
  int row=row0+rg;
  int b=row>>14, n=(row>>6)&255, t=row&63;
  size_t oidx = (((size_t)(b*Tq+t)*Nq)+n)*64 + dp0;
  *(float4*)&out[oidx] = make_float4(acc.x+b4.x, acc.y+b4.y, acc.z+b4.z, acc.w+b4.w);
}

extern "C" void kernel_launch(void* const* d_in, const int* in_sizes, int n_in,
                              void* d_out, int out_size, void* d_ws, size_t ws_size,
                              hipStream_t stream) {
  const float* X    = (const float*)d_in[0];
  const float* A    = (const float*)d_in[1];
  const float* he   = (const float*)d_in[2];
  const float* Gl   = (const float*)d_in[3];
  const float* Wq   = (const float*)d_in[4];
  const float* Wk   = (const float*)d_in[5];
  const float* nodeW= (const float*)d_in[6];
  const float* nodeB= (const float*)d_in[7];
  const float* sW   = (const float*)d_in[8];
  const float* sB   = (const float*)d_in[9];
  const float* filtW= (const float*)d_in[10];
  const float* filtB= (const float*)d_in[11];
  const float* gateW= (const float*)d_in[12];
  const float* gateB= (const float*)d_in[13];
  const float* skipW= (const float*)d_in[14];
  const float* skipB= (const float*)d_in[15];
  const float* convW= (const float*)d_in[16];
  const float* convWg=(const float*)d_in[17];
  const float* Wfuse= (const float*)d_in[18];
  const float* Wgfuse=(const float*)d_in[19];
  const float* outW = (const float*)d_in[20];
  const float* outB = (const float*)d_in[21];
  const float* gamma= (const float*)d_in[22];
  const float* beta = (const float*)d_in[23];
  const float* endW = (const float*)d_in[24];
  const float* endB = (const float*)d_in[25];
  float* ws  = (float*)d_ws;
  float* out = (float*)d_out;
  if (ws_size < (size_t)WS_FLOATS*sizeof(float)) return;  // insufficient scratch

  float* Qb = ws+O_Q;  float* Kb = ws+O_K;  float* Hd = ws+O_HD;
  float* iDd= ws+O_IDD; float* iBd= ws+O_IBD;
  float* Hg = ws+O_HG; float* iDg= ws+O_IDG; float* iBg= ws+O_IBG;
  float* An = ws+O_AN; float* Ag = ws+O_AG;
  float* WfT= ws+O_WFT; float* WgT= ws+O_WGT; float* WoT= ws+O_WOT; float* WeT= ws+O_WET;
  float* FtT= ws+O_FTT; float* GtT= ws+O_GTT; float* StT= ws+O_STT;
  float* big= ws+O_BIG;
  float* x   = big;
  float* xf  = big + (size_t)ELEMS;
  float* skip= big + (size_t)2*ELEMS;
  float* p1  = big + (size_t)3*ELEMS;
  float* p2  = big + (size_t)4*ELEMS;
  float* p3  = big + (size_t)5*ELEMS;

  k_tw<<<13,256,0,stream>>>(Wfuse,Wgfuse,outW,endW,filtW,gateW,skipW,ws);
  k_q<<<Bq*Nq,64,0,stream>>>(X,nodeW,nodeB,Wq,Qb);
  k_k<<<Eq,64,0,stream>>>(he,Wk,Kb);
  k_h<<<Bq*Nq,128,0,stream>>>(Qb,Kb,Hd,iDd);
  k_bd<<<2,256,0,stream>>>(Hd,iBd);
  k_hgeo<<<Nq,128,0,stream>>>(A,Gl,Hg,iDg);
  k_bg<<<1,128,0,stream>>>(Hg,iBg);
  k_anorm<<<Bq*Nq,256,0,stream>>>(Hd,iDd,iBd,An);
  k_ageo<<<Nq,256,0,stream>>>(Hg,iDg,iBg,Ag);
  k_start<<<ELEMS/1024,256,0,stream>>>(X,sW,sB,x,skip);

  for (int i=0;i<3;i++){
    k_fg<<<Rq/16,256,0,stream>>>(x, FtT+i*4096, GtT+i*4096, StT+i*4096,
        filtB+i*64, gateB+i*64, skipB+i*64, xf, skip);
    // xd/xg chains (xd2 lands in the now-dead x buffer)
    k_spatial<<<1024,256,0,stream>>>(An, Nq*Nq, xf, convW,        p1); // XD
    k_spatial<<<1024,256,0,stream>>>(Ag, 0,     xf, convWg,       p2); // XG
    k_spatial<<<1024,256,0,stream>>>(An, Nq*Nq, p1, convW+4096,   x ); // XD2
    k_spatial<<<1024,256,0,stream>>>(Ag, 0,     p2, convWg+4096,  p3); // XG2
    k_combine<<<Rq/16,256,0,stream>>>(p1, p2, xf, WfT, WgT);  // OUT0 (in p1)
    k_combine<<<Rq/16,256,0,stream>>>(x,  p3, xf, WfT, WgT);  // OUT1 (in x)
    k_out<<<Rq/16,256,0,stream>>>(p1, x, WoT, outB, gamma, beta, p2); // new x = p2
    // rotate buffers for next layer
    float* nx = p2; float* nxf = x; float* np1 = xf; float* np2 = p1;
    x=nx; xf=nxf; p1=np1; p2=np2; /* p3 unchanged */
  }
  k_end<<<Rq/16,256,0,stream>>>(skip, WeT, endB, out);
}

// Round 6
// 629.623 us; speedup vs baseline: 2.2225x; 2.2225x over previous
//
#include <hip/hip_runtime.h>
#include <math.h>

// Problem dims
#define Bq 4
#define Tq 64
#define Nq 256
#define Eq 128
#define Dq 64
#define Rq (Bq*Nq*Tq)      // 65536 rows (b,n,t)
#define ELEMS (Rq*Dq)      // 4194304

// ws offsets (in floats)
#define O_Q    0
#define O_K    65536
#define O_HD   73728
#define O_IDD  204800
#define O_IBD  205824
#define O_HG   206336
#define O_IDG  239104
#define O_IBG  239360
#define O_AN   239488
#define O_AG   501632
#define O_WFT  567168      // MFMA weight-fragment area
#define O_BIG  632704
#define WS_FLOATS (O_BIG + 6*ELEMS)

// fragment sub-offsets (floats, relative to ws+O_WFT)
#define FR_FILT 0          // 3 x 2048
#define FR_GATE 6144       // 3 x 2048
#define FR_SKIP 12288      // 3 x 2048
#define FR_WFA  18432      // 2048
#define FR_WGA  20480      // 2048
#define FR_WBB  22528      // 2048 (WfB + WgB)
#define FR_WO   24576      // 4096 (K=128)
#define FR_WE   28672      // 2048
#define FR_CW0  30720      // 2048 convW[0]^T
#define FR_CW1  32768      // 2048 convW[1]^T
#define FR_CG0  34816      // 2048 convWg[0]^T
#define FR_CG1  36864      // 2048 convWg[1]^T

typedef __attribute__((ext_vector_type(8))) short bf16x8;
typedef __attribute__((ext_vector_type(4))) float f32x4;
#define MFMA16(a,b,c) __builtin_amdgcn_mfma_f32_16x16x32_bf16(a,b,c,0,0,0)

__device__ __forceinline__ float sigmoidf_(float x){ return 1.f/(1.f+expf(-x)); }

__device__ __forceinline__ short bf(float x){
  union{float f; unsigned u;} v; v.f=x;
  unsigned r=(v.u + 0x7FFFu + ((v.u>>16)&1u))>>16;
  return (short)r;
}

__device__ __forceinline__ bf16x8 cvt8(const float* p){
  float4 a=*(const float4*)p; float4 b=*(const float4*)(p+4);
  bf16x8 r;
  r[0]=bf(a.x); r[1]=bf(a.y); r[2]=bf(a.z); r[3]=bf(a.w);
  r[4]=bf(b.x); r[5]=bf(b.y); r[6]=bf(b.z); r[7]=bf(b.w);
  return r;
}

// ---------------- weight fragment precompute (once per launch) ----------------
// direct: frag = W[16*dt+m][32*kc+8*g+i]   (for x @ W.T patterns)
// transposed (tr): frag = W[32*kc+8*g+i][16*dt+m]  (for x @ W patterns: convW)
__global__ __launch_bounds__(64) void k_wfrag(
    const float* __restrict__ filtW, const float* __restrict__ gateW,
    const float* __restrict__ skipW, const float* __restrict__ Wfuse,
    const float* __restrict__ Wgfuse, const float* __restrict__ outW,
    const float* __restrict__ endW, const float* __restrict__ convW,
    const float* __restrict__ convWg, float* __restrict__ ws){
  int job=blockIdx.x, l=threadIdx.x;
  const float* s1; const float* s2=nullptr; int stride=64, KC=2, tr=0; float* dst;
  float* fr = ws + O_WFT;
  if      (job<3){ s1=filtW+job*4096;     stride=64;  dst=fr+FR_FILT+job*2048; }
  else if (job<6){ s1=gateW+(job-3)*4096; stride=64;  dst=fr+FR_GATE+(job-3)*2048; }
  else if (job<9){ s1=skipW+(job-6)*4096; stride=64;  dst=fr+FR_SKIP+(job-6)*2048; }
  else if (job==9){  s1=Wfuse;            stride=128; dst=fr+FR_WFA; }
  else if (job==10){ s1=Wgfuse;           stride=128; dst=fr+FR_WGA; }
  else if (job==11){ s1=Wfuse+64; s2=Wgfuse+64; stride=128; dst=fr+FR_WBB; }
  else if (job==12){ s1=outW;             stride=128; KC=4; dst=fr+FR_WO; }
  else if (job==13){ s1=endW;             stride=64;  dst=fr+FR_WE; }
  else { int q=job-14; tr=1;
         s1 = (q<2) ? (convW + q*4096) : (convWg + (q-2)*4096);
         dst = fr + FR_CW0 + q*2048; }
  int m=l&15, g=l>>4;
  for (int dt=0; dt<4; ++dt) for (int kc=0; kc<KC; ++kc){
    unsigned short* d = (unsigned short*)(dst + ((size_t)(dt*KC+kc)*64 + l)*4);
    for (int i=0;i<8;i++){
      float v;
      if (tr) v = s1[(32*kc+8*g+i)*64 + (16*dt+m)];
      else {
        v = s1[(16*dt+m)*stride + 32*kc + 8*g + i];
        if (s2) v += s2[(16*dt+m)*stride + 32*kc + 8*g + i];
      }
      d[i] = (unsigned short)bf(v);
    }
  }
}

// ---------------- phase 0: hypergraph construction (unchanged fp32) ----------------
__global__ __launch_bounds__(64) void k_q(const float* __restrict__ X,
    const float* __restrict__ nodeW, const float* __restrict__ nodeB,
    const float* __restrict__ Wq, float* __restrict__ Q) {
  int bn = blockIdx.x; int b = bn >> 8; int n = bn & 255;
  int tid = threadIdx.x;
  __shared__ float xcol[Tq];
  __shared__ float ee[Dq];
  xcol[tid] = X[(b*Tq + tid)*Nq + n];
  __syncthreads();
  float acc = 0.f;
  #pragma unroll 8
  for (int t=0;t<Tq;t++) acc += xcol[t]*nodeW[tid*Tq+t];
  ee[tid] = acc + nodeB[tid];
  __syncthreads();
  float q = 0.f;
  #pragma unroll 8
  for (int d=0; d<Dq; d++) q += ee[d]*Wq[tid*Dq+d];
  Q[bn*Dq+tid] = q;
}

__global__ __launch_bounds__(64) void k_k(const float* __restrict__ he,
    const float* __restrict__ Wk, float* __restrict__ K) {
  int e = blockIdx.x; int tid = threadIdx.x;
  __shared__ float hr[Dq];
  hr[tid] = he[e*Dq+tid];
  __syncthreads();
  float acc = 0.f;
  #pragma unroll 8
  for (int d=0; d<Dq; d++) acc += hr[d]*Wk[tid*Dq+d];
  K[e*Dq+tid] = acc;
}

__global__ __launch_bounds__(128) void k_h(const float* __restrict__ Q,
    const float* __restrict__ K, float* __restrict__ H, float* __restrict__ invDd) {
  int bn = blockIdx.x; int tid = threadIdx.x;
  __shared__ float qr[Dq];
  __shared__ float red[Eq];
  if (tid < Dq) qr[tid] = Q[bn*Dq+tid];
  __syncthreads();
  float s = 0.f;
  const float* kr = K + tid*Dq;
  #pragma unroll 8
  for (int d=0; d<Dq; d++) s += qr[d]*kr[d];
  s *= 0.125f;
  red[tid] = s; __syncthreads();
  for (int off=64; off>0; off>>=1){ if (tid<off) red[tid]=fmaxf(red[tid],red[tid+off]); __syncthreads(); }
  float mx = red[0]; __syncthreads();
  float e = expf(s-mx);
  red[tid] = e; __syncthreads();
  for (int off=64; off>0; off>>=1){ if (tid<off) red[tid]+=red[tid+off]; __syncthreads(); }
  float sm = red[0]; __syncthreads();
  float h = e/sm;
  H[bn*Eq+tid] = h;
  red[tid]=h; __syncthreads();
  for (int off=64; off>0; off>>=1){ if (tid<off) red[tid]+=red[tid+off]; __syncthreads(); }
  if (tid==0){ float dd = red[0]; invDd[bn] = dd>0.f ? 1.f/(dd+1e-8f) : 0.f; }
}

__global__ __launch_bounds__(256) void k_bd(const float* __restrict__ H,
    float* __restrict__ invBd) {
  int idx = blockIdx.x*256 + threadIdx.x;
  if (idx >= Bq*Eq) return;
  int b = idx >> 7; int e = idx & 127;
  float s=0.f;
  for (int n=0;n<Nq;n++) s += H[(b*Nq+n)*Eq + e];
  invBd[idx] = s>0.f ? 1.f/(s+1e-8f) : 0.f;
}

__global__ __launch_bounds__(128) void k_hgeo(const float* __restrict__ A,
    const float* __restrict__ Gl, float* __restrict__ Hg, float* __restrict__ invDg) {
  int n = blockIdx.x; int tid = threadIdx.x;
  __shared__ float ar[Nq];
  __shared__ float red[Eq];
  ar[tid] = A[n*Nq+tid]; ar[tid+128] = A[n*Nq+128+tid];
  __syncthreads();
  float s=0.f;
  #pragma unroll 4
  for (int k=0;k<Nq;k++) s += ar[k]*Gl[k*Eq+tid];
  Hg[n*Eq+tid] = s;
  red[tid]=s; __syncthreads();
  for (int off=64; off>0; off>>=1){ if (tid<off) red[tid]+=red[tid+off]; __syncthreads(); }
  if (tid==0){ float dg=red[0]; invDg[n] = dg>0.f ? 1.f/(dg+1e-8f):0.f; }
}

__global__ __launch_bounds__(128) void k_bg(const float* __restrict__ Hg,
    float* __restrict__ invBg){
  int e = threadIdx.x;
  float s=0.f;
  for (int n=0;n<Nq;n++) s += Hg[n*Eq+e];
  invBg[e] = s>0.f ? 1.f/(s+1e-8f) : 0.f;
}

__global__ __launch_bounds__(256) void k_anorm(const float* __restrict__ H,
    const float* __restrict__ invDd, const float* __restrict__ invBd,
    float* __restrict__ An) {
  int bid = blockIdx.x; int b = bid>>8; int i = bid&255; int j = threadIdx.x;
  __shared__ float hr[Eq];
  if (j < Eq) hr[j] = H[(b*Nq+i)*Eq+j] * invBd[b*Eq+j];
  __syncthreads();
  const float* hj = H + (b*Nq+j)*Eq;
  float s=0.f;
  #pragma unroll 8
  for (int e=0;e<Eq;e++) s += hr[e]*hj[e];
  An[(b*Nq+i)*Nq + j] = invDd[b*Nq+i]*s;
}

__global__ __launch_bounds__(256) void k_ageo(const float* __restrict__ Hg,
    const float* __restrict__ invDg, const float* __restrict__ invBg,
    float* __restrict__ Ag) {
  int i = blockIdx.x; int j = threadIdx.x;
  __shared__ float hr[Eq];
  if (j<Eq) hr[j] = Hg[i*Eq+j]*invBg[j];
  __syncthreads();
  const float* hj = Hg + j*Eq;
  float s=0.f;
  #pragma unroll 8
  for (int e=0;e<Eq;e++) s+=hr[e]*hj[e];
  Ag[i*Nq+j] = invDg[i]*s;
}

// ---------------- start (unchanged) ----------------
__global__ __launch_bounds__(256) void k_start(const float* __restrict__ X,
    const float* __restrict__ sW, const float* __restrict__ sB,
    float* __restrict__ x, float* __restrict__ skip) {
  int idx4 = blockIdx.x*256+threadIdx.x;
  int base = idx4*4;
  int row = base>>6, d0 = base&63;
  int b = row>>14, n = (row>>6)&255, t = row&63;
  float xv = X[(b*Tq+t)*Nq + n];
  float4 w = *(const float4*)&sW[d0];
  float4 bb = *(const float4*)&sB[d0];
  float4 v = make_float4(xv*w.x+bb.x, xv*w.y+bb.y, xv*w.z+bb.z, xv*w.w+bb.w);
  *(float4*)&x[base] = v;
  *(float4*)&skip[base] = v;
}

// ---------------- MFMA row-family ----------------
// Y^T = W @ X^T tiles: wave w handles 16 rows; lane: m=l&15 (row), g=l>>4.
// C layout: lane holds (row m, d = 16*dt + 4*g + j), j=0..3 per dt-tile.

// fg: xf = tanh(x@Wf.T+fb)*sig(x@Wg.T+gb); skip += xf@Ws.T+sb;
//     ALSO (associativity fold): xw = xf@convW[0], xwg = xf@convWg[0]
__global__ __launch_bounds__(256) void k_fg_m(
    const float* __restrict__ x, const float* __restrict__ ws,
    const float* __restrict__ fb, const float* __restrict__ gb,
    const float* __restrict__ sb, int layer,
    float* __restrict__ xf, float* __restrict__ skip,
    float* __restrict__ xw, float* __restrict__ xwg){
  __shared__ unsigned short smem[4][16*72];
  int tid=threadIdx.x, w=tid>>6, l=tid&63, m=l&15, g=l>>4;
  const bf16x8* FF=(const bf16x8*)(ws+O_WFT+FR_FILT)+(size_t)layer*512;
  const bf16x8* FG=(const bf16x8*)(ws+O_WFT+FR_GATE)+(size_t)layer*512;
  const bf16x8* FS=(const bf16x8*)(ws+O_WFT+FR_SKIP)+(size_t)layer*512;
  const bf16x8* CW0=(const bf16x8*)(ws+O_WFT+FR_CW0);
  const bf16x8* CG0=(const bf16x8*)(ws+O_WFT+FR_CG0);
  int r = blockIdx.x*64 + w*16 + m;
  const float* xr = x + (size_t)r*64;
  bf16x8 xb0=cvt8(xr+8*g), xb1=cvt8(xr+32+8*g);
  f32x4 z; z[0]=0.f; z[1]=0.f; z[2]=0.f; z[3]=0.f;
  #pragma unroll
  for(int dt=0;dt<4;dt++){
    f32x4 aF=MFMA16(FF[(dt*2+1)*64+l],xb1,MFMA16(FF[(dt*2+0)*64+l],xb0,z));
    f32x4 aG=MFMA16(FG[(dt*2+1)*64+l],xb1,MFMA16(FG[(dt*2+0)*64+l],xb0,z));
    float4 fb4=*(const float4*)&fb[16*dt+4*g];
    float4 gb4=*(const float4*)&gb[16*dt+4*g];
    float y0=tanhf(aF[0]+fb4.x)*sigmoidf_(aG[0]+gb4.x);
    float y1=tanhf(aF[1]+fb4.y)*sigmoidf_(aG[1]+gb4.y);
    float y2=tanhf(aF[2]+fb4.z)*sigmoidf_(aG[2]+gb4.z);
    float y3=tanhf(aF[3]+fb4.w)*sigmoidf_(aG[3]+gb4.w);
    *(float4*)&xf[(size_t)r*64+16*dt+4*g]=make_float4(y0,y1,y2,y3);
    *(ushort4*)&smem[w][m*72+16*dt+4*g]=make_ushort4(
        (unsigned short)bf(y0),(unsigned short)bf(y1),
        (unsigned short)bf(y2),(unsigned short)bf(y3));
  }
  __syncthreads();
  bf16x8 yb0=*(const bf16x8*)&smem[w][m*72+8*g];
  bf16x8 yb1=*(const bf16x8*)&smem[w][m*72+32+8*g];
  #pragma unroll
  for(int dt=0;dt<4;dt++){
    f32x4 aS=MFMA16(FS[(dt*2+1)*64+l],yb1,MFMA16(FS[(dt*2+0)*64+l],yb0,z));
    float4 sb4=*(const float4*)&sb[16*dt+4*g];
    size_t o=(size_t)r*64+16*dt+4*g;
    float4 sv=*(float4*)&skip[o];
    sv.x+=aS[0]+sb4.x; sv.y+=aS[1]+sb4.y; sv.z+=aS[2]+sb4.z; sv.w+=aS[3]+sb4.w;
    *(float4*)&skip[o]=sv;
  }
  #pragma unroll
  for(int dt=0;dt<4;dt++){
    f32x4 aW=MFMA16(CW0[(dt*2+1)*64+l],yb1,MFMA16(CW0[(dt*2+0)*64+l],yb0,z));
    *(float4*)&xw[(size_t)r*64+16*dt+4*g]=make_float4(aW[0],aW[1],aW[2],aW[3]);
    f32x4 aH=MFMA16(CG0[(dt*2+1)*64+l],yb1,MFMA16(CG0[(dt*2+0)*64+l],yb0,z));
    *(float4*)&xwg[(size_t)r*64+16*dt+4*g]=make_float4(aH[0],aH[1],aH[2],aH[3]);
  }
}

// combine: xd <- V*xd + (1-V)*xg, V=sig(xd@WfA.T + xg@WgA.T + xs@(WfB+WgB).T)
// if ep: also wA = xd@convW[1], wB = xg@convWg[1] (pre-overwrite values)
__global__ __launch_bounds__(256) void k_comb_m(
    float* __restrict__ xd, const float* __restrict__ xg,
    const float* __restrict__ xs, const float* __restrict__ ws,
    int ep, float* __restrict__ wA, float* __restrict__ wB){
  int tid=threadIdx.x, w=tid>>6, l=tid&63, m=l&15, g=l>>4;
  const bf16x8* FA=(const bf16x8*)(ws+O_WFT+FR_WFA);
  const bf16x8* GA=(const bf16x8*)(ws+O_WFT+FR_WGA);
  const bf16x8* BB=(const bf16x8*)(ws+O_WFT+FR_WBB);
  int r=blockIdx.x*64+w*16+m;
  const float* pd=xd+(size_t)r*64;
  const float* pg=xg+(size_t)r*64;
  const float* p0=xs+(size_t)r*64;
  bf16x8 d0=cvt8(pd+8*g), d1=cvt8(pd+32+8*g);
  bf16x8 g0=cvt8(pg+8*g), g1=cvt8(pg+32+8*g);
  bf16x8 s0=cvt8(p0+8*g), s1=cvt8(p0+32+8*g);
  f32x4 z; z[0]=0.f; z[1]=0.f; z[2]=0.f; z[3]=0.f;
  #pragma unroll
  for(int dt=0;dt<4;dt++){
    f32x4 a=MFMA16(FA[(dt*2+0)*64+l],d0,z);
    a=MFMA16(FA[(dt*2+1)*64+l],d1,a);
    a=MFMA16(GA[(dt*2+0)*64+l],g0,a);
    a=MFMA16(GA[(dt*2+1)*64+l],g1,a);
    a=MFMA16(BB[(dt*2+0)*64+l],s0,a);
    a=MFMA16(BB[(dt*2+1)*64+l],s1,a);
    size_t o=(size_t)r*64+16*dt+4*g;
    float4 dv=*(const float4*)&xd[o];
    float4 gv=*(const float4*)&xg[o];
    float V0=sigmoidf_(a[0]), V1=sigmoidf_(a[1]), V2=sigmoidf_(a[2]), V3=sigmoidf_(a[3]);
    float4 ov=make_float4(V0*dv.x+(1.f-V0)*gv.x, V1*dv.y+(1.f-V1)*gv.y,
                          V2*dv.z+(1.f-V2)*gv.z, V3*dv.w+(1.f-V3)*gv.w);
    *(float4*)&xd[o]=ov;
  }
  if (ep){
    const bf16x8* CW1=(const bf16x8*)(ws+O_WFT+FR_CW1);
    const bf16x8* CG1=(const bf16x8*)(ws+O_WFT+FR_CG1);
    #pragma unroll
    for(int dt=0;dt<4;dt++){
      f32x4 a1=MFMA16(CW1[(dt*2+1)*64+l],d1,MFMA16(CW1[(dt*2+0)*64+l],d0,z));
      *(float4*)&wA[(size_t)r*64+16*dt+4*g]=make_float4(a1[0],a1[1],a1[2],a1[3]);
      f32x4 a2=MFMA16(CG1[(dt*2+1)*64+l],g1,MFMA16(CG1[(dt*2+0)*64+l],g0,z));
      *(float4*)&wB[(size_t)r*64+16*dt+4*g]=make_float4(a2[0],a2[1],a2[2],a2[3]);
    }
  }
}

__global__ __launch_bounds__(256) void k_out_m(
    const float* __restrict__ o0, const float* __restrict__ o1,
    const float* __restrict__ ws, const float* __restrict__ ob,
    const float* __restrict__ gamma, const float* __restrict__ beta,
    float* __restrict__ xn){
  int tid=threadIdx.x, w=tid>>6, l=tid&63, m=l&15, g=l>>4;
  const bf16x8* WO=(const bf16x8*)(ws+O_WFT+FR_WO);
  int r=blockIdx.x*64+w*16+m;
  const float* a0=o0+(size_t)r*64;
  const float* a1=o1+(size_t)r*64;
  bf16x8 b0=cvt8(a0+8*g), b1=cvt8(a0+32+8*g), b2=cvt8(a1+8*g), b3=cvt8(a1+32+8*g);
  f32x4 z; z[0]=0.f; z[1]=0.f; z[2]=0.f; z[3]=0.f;
  float y[4][4]; float s=0.f;
  #pragma unroll
  for(int dt=0;dt<4;dt++){
    f32x4 a=MFMA16(WO[(dt*4+0)*64+l],b0,z);
    a=MFMA16(WO[(dt*4+1)*64+l],b1,a);
    a=MFMA16(WO[(dt*4+2)*64+l],b2,a);
    a=MFMA16(WO[(dt*4+3)*64+l],b3,a);
    float4 bb=*(const float4*)&ob[16*dt+4*g];
    y[dt][0]=a[0]+bb.x; y[dt][1]=a[1]+bb.y; y[dt][2]=a[2]+bb.z; y[dt][3]=a[3]+bb.w;
    s+=y[dt][0]+y[dt][1]+y[dt][2]+y[dt][3];
  }
  s+=__shfl_xor(s,16); s+=__shfl_xor(s,32);
  float mean=s*(1.f/64.f);
  float q=0.f;
  #pragma unroll
  for(int dt=0;dt<4;dt++){
    #pragma unroll
    for(int j=0;j<4;j++){ float e=y[dt][j]-mean; q+=e*e; }
  }
  q+=__shfl_xor(q,16); q+=__shfl_xor(q,32);
  float rstd=rsqrtf(q*(1.f/64.f)+1e-5f);
  #pragma unroll
  for(int dt=0;dt<4;dt++){
    float4 g4=*(const float4*)&gamma[16*dt+4*g];
    float4 be4=*(const float4*)&beta[16*dt+4*g];
    float4 o=make_float4((y[dt][0]-mean)*rstd*g4.x+be4.x,
                         (y[dt][1]-mean)*rstd*g4.y+be4.y,
                         (y[dt][2]-mean)*rstd*g4.z+be4.z,
                         (y[dt][3]-mean)*rstd*g4.w+be4.w);
    *(float4*)&xn[(size_t)r*64+16*dt+4*g]=o;
  }
}

__global__ __launch_bounds__(256) void k_end_m(
    const float* __restrict__ skip, const float* __restrict__ ws,
    const float* __restrict__ eb, float* __restrict__ out){
  int tid=threadIdx.x, w=tid>>6, l=tid&63, m=l&15, g=l>>4;
  const bf16x8* WE=(const bf16x8*)(ws+O_WFT+FR_WE);
  int r=blockIdx.x*64+w*16+m;
  const float* sr=skip+(size_t)r*64;
  float t0[8], t1[8];
  {
    float4 a=*(const float4*)(sr+8*g), b=*(const float4*)(sr+8*g+4);
    t0[0]=fmaxf(a.x,0.f); t0[1]=fmaxf(a.y,0.f); t0[2]=fmaxf(a.z,0.f); t0[3]=fmaxf(a.w,0.f);
    t0[4]=fmaxf(b.x,0.f); t0[5]=fmaxf(b.y,0.f); t0[6]=fmaxf(b.z,0.f); t0[7]=fmaxf(b.w,0.f);
    float4 c=*(const float4*)(sr+32+8*g), d=*(const float4*)(sr+32+8*g+4);
    t1[0]=fmaxf(c.x,0.f); t1[1]=fmaxf(c.y,0.f); t1[2]=fmaxf(c.z,0.f); t1[3]=fmaxf(c.w,0.f);
    t1[4]=fmaxf(d.x,0.f); t1[5]=fmaxf(d.y,0.f); t1[6]=fmaxf(d.z,0.f); t1[7]=fmaxf(d.w,0.f);
  }
  bf16x8 s0,s1;
  #pragma unroll
  for(int i=0;i<8;i++){ s0[i]=bf(t0[i]); s1[i]=bf(t1[i]); }
  f32x4 z; z[0]=0.f; z[1]=0.f; z[2]=0.f; z[3]=0.f;
  int b_=r>>14, n_=(r>>6)&255, t_=r&63;
  size_t obase=((size_t)(b_*Tq+t_)*Nq+n_)*64;
  #pragma unroll
  for(int dt=0;dt<4;dt++){
    f32x4 a=MFMA16(WE[(dt*2+1)*64+l],s1,MFMA16(WE[(dt*2+0)*64+l],s0,z));
    float4 bb=*(const float4*)&eb[16*dt+4*g];
    *(float4*)&out[obase+16*dt+4*g]=make_float4(a[0]+bb.x,a[1]+bb.y,a[2]+bb.z,a[3]+bb.w);
  }
}

// ---------------- spatial: out = Adj(256x256) @ in (pure adjacency, MFMA) ----------------
// block: 4 waves; M-tile=64 (wave w: 16 rows), C-tile=64 (one t0, all d).
// A-operand = Adj rows (n-contiguous, direct from global via cvt8).
// B-operand = in^T staged in LDS: ldsT[d][n] bf16, stride 264 (b128-aligned).
__global__ __launch_bounds__(256) void k_adj_m(const float* __restrict__ Adj,
    int adjStride, const float* __restrict__ in, float* __restrict__ out){
  __shared__ unsigned short ldsT[64*264];   // 33792 B
  int tid=threadIdx.x, w=tid>>6, l=tid&63, m=l&15, g=l>>4;
  int t0 = blockIdx.x & 63, mc=(blockIdx.x>>6)&3, b = blockIdx.x>>8;
  const float* Ar = Adj + (size_t)b*adjStride + (size_t)(mc*64 + w*16 + m)*256;
  bf16x8 afr[8];
  #pragma unroll
  for (int kc=0;kc<8;kc++) afr[kc] = cvt8(Ar + kc*32 + g*8);
  // stage in-tile transposed: thread covers (4 n) x (4 d) sub-block per iter
  int dq=(tid&15)*4, ng=(tid>>4)*4;
  #pragma unroll
  for (int iter=0; iter<4; ++iter){
    int n0 = iter*64 + ng;
    const float* base = in + (((size_t)b*Nq + n0)*Tq + t0)*Dq + dq;
    float4 v0 = *(const float4*)(base);
    float4 v1 = *(const float4*)(base + 4096);
    float4 v2 = *(const float4*)(base + 8192);
    float4 v3 = *(const float4*)(base + 12288);
    *(ushort4*)&ldsT[(dq+0)*264 + n0] = make_ushort4(
      (unsigned short)bf(v0.x),(unsigned short)bf(v1.x),
      (unsigned short)bf(v2.x),(unsigned short)bf(v3.x));
    *(ushort4*)&ldsT[(dq+1)*264 + n0] = make_ushort4(
      (unsigned short)bf(v0.y),(unsigned short)bf(v1.y),
      (unsigned short)bf(v2.y),(unsigned short)bf(v3.y));
    *(ushort4*)&ldsT[(dq+2)*264 + n0] = make_ushort4(
      (unsigned short)bf(v0.z),(unsigned short)bf(v1.z),
      (unsigned short)bf(v2.z),(unsigned short)bf(v3.z));
    *(ushort4*)&ldsT[(dq+3)*264 + n0] = make_ushort4(
      (unsigned short)bf(v0.w),(unsigned short)bf(v1.w),
      (unsigned short)bf(v2.w),(unsigned short)bf(v3.w));
  }
  __syncthreads();
  f32x4 z; z[0]=0.f; z[1]=0.f; z[2]=0.f; z[3]=0.f;
  f32x4 acc[4] = {z,z,z,z};
  #pragma unroll
  for (int kc=0;kc<8;kc++){
    #pragma unroll
    for (int ct=0;ct<4;ct++){
      bf16x8 bfr = *(const bf16x8*)&ldsT[(ct*16+m)*264 + kc*32 + g*8];
      acc[ct]=MFMA16(afr[kc], bfr, acc[ct]);
    }
  }
  // D layout: lane holds out[M = mc*64+w*16+4g+j][d = ct*16+m]
  size_t ob = (((size_t)b*Nq + mc*64 + w*16 + 4*g)*Tq + t0)*Dq;
  #pragma unroll
  for (int ct=0;ct<4;ct++){
    #pragma unroll
    for (int j=0;j<4;j++){
      out[ob + (size_t)j*Tq*Dq + ct*16 + m] = acc[ct][j];
    }
  }
}

extern "C" void kernel_launch(void* const* d_in, const int* in_sizes, int n_in,
                              void* d_out, int out_size, void* d_ws, size_t ws_size,
                              hipStream_t stream) {
  const float* X    = (const float*)d_in[0];
  const float* A    = (const float*)d_in[1];
  const float* he   = (const float*)d_in[2];
  const float* Gl   = (const float*)d_in[3];
  const float* Wq   = (const float*)d_in[4];
  const float* Wk   = (const float*)d_in[5];
  const float* nodeW= (const float*)d_in[6];
  const float* nodeB= (const float*)d_in[7];
  const float* sW   = (const float*)d_in[8];
  const float* sB   = (const float*)d_in[9];
  const float* filtW= (const float*)d_in[10];
  const float* filtB= (const float*)d_in[11];
  const float* gateW= (const float*)d_in[12];
  const float* gateB= (const float*)d_in[13];
  const float* skipW= (const float*)d_in[14];
  const float* skipB= (const float*)d_in[15];
  const float* convW= (const float*)d_in[16];
  const float* convWg=(const float*)d_in[17];
  const float* Wfuse= (const float*)d_in[18];
  const float* Wgfuse=(const float*)d_in[19];
  const float* outW = (const float*)d_in[20];
  const float* outB = (const float*)d_in[21];
  const float* gamma= (const float*)d_in[22];
  const float* beta = (const float*)d_in[23];
  const float* endW = (const float*)d_in[24];
  const float* endB = (const float*)d_in[25];
  float* ws  = (float*)d_ws;
  float* out = (float*)d_out;
  if (ws_size < (size_t)WS_FLOATS*sizeof(float)) return;

  float* Qb = ws+O_Q;  float* Kb = ws+O_K;  float* Hd = ws+O_HD;
  float* iDd= ws+O_IDD; float* iBd= ws+O_IBD;
  float* Hg = ws+O_HG; float* iDg= ws+O_IDG; float* iBg= ws+O_IBG;
  float* An = ws+O_AN; float* Ag = ws+O_AG;
  float* big= ws+O_BIG;
  // 6 big buffers; b2 = skip (persistent)
  float* skip = big + (size_t)2*ELEMS;
  float* sx   = big;                       // layer input x
  float* sxf  = big + (size_t)1*ELEMS;     // xf
  float* sw0  = big + (size_t)3*ELEMS;     // xf@convW0 -> xg1 -> xd2 -> OUT1
  float* swg0 = big + (size_t)4*ELEMS;     // xf@convWg0 -> xg1@convWg1 -> newx
  float* sxd1 = big + (size_t)5*ELEMS;     // xd1 -> OUT0

  k_wfrag<<<18,64,0,stream>>>(filtW,gateW,skipW,Wfuse,Wgfuse,outW,endW,convW,convWg,ws);
  k_q<<<Bq*Nq,64,0,stream>>>(X,nodeW,nodeB,Wq,Qb);
  k_k<<<Eq,64,0,stream>>>(he,Wk,Kb);
  k_h<<<Bq*Nq,128,0,stream>>>(Qb,Kb,Hd,iDd);
  k_bd<<<2,256,0,stream>>>(Hd,iBd);
  k_hgeo<<<Nq,128,0,stream>>>(A,Gl,Hg,iDg);
  k_bg<<<1,128,0,stream>>>(Hg,iBg);
  k_anorm<<<Bq*Nq,256,0,stream>>>(Hd,iDd,iBd,An);
  k_ageo<<<Nq,256,0,stream>>>(Hg,iDg,iBg,Ag);
  k_start<<<ELEMS/1024,256,0,stream>>>(X,sW,sB,sx,skip);

  for (int i=0;i<3;i++){
    // fg: xf, skip+=, and pre-conv'd spatial inputs xf@W0 / xf@Wg0
    k_fg_m<<<Rq/64,256,0,stream>>>(sx, ws, filtB+i*64, gateB+i*64, skipB+i*64, i,
                                   sxf, skip, sw0, swg0);
    // depth 0: xd1 = An (x) (xf@W0); xg1 = Ag (x) (xf@Wg0)
    k_adj_m<<<1024,256,0,stream>>>(An, Nq*Nq, sw0, sxd1);        // xd1 (sw0 dead)
    k_adj_m<<<1024,256,0,stream>>>(Ag, 0,     swg0, sw0);        // xg1 (swg0 dead)
    // comb1: OUT0 in-place(sxd1); epilogue: xd1@W1 -> sx, xg1@Wg1 -> swg0
    k_comb_m<<<Rq/64,256,0,stream>>>(sxd1, sw0, sxf, ws, 1, sx, swg0);
    // depth 1: xd2 = An (x) (xd1@W1); xg2 = Ag (x) (xg1@Wg1)
    k_adj_m<<<1024,256,0,stream>>>(An, Nq*Nq, sx,  sw0);         // xd2 (sw0=xg1 dead)
    k_adj_m<<<1024,256,0,stream>>>(Ag, 0,     swg0, sx);         // xg2 (sx dead)
    // comb2: OUT1 in-place(sw0)
    k_comb_m<<<Rq/64,256,0,stream>>>(sw0, sx, sxf, ws, 0, nullptr, nullptr);
    // out-proj + LN: newx -> swg0
    k_out_m<<<Rq/64,256,0,stream>>>(sxd1, sw0, ws, outB, gamma, beta, swg0);
    // rotate slots: x' = swg0(newx); swg0' = sxd1(dead); sxd1' = sx(dead)
    float* t = sx; sx = swg0; swg0 = sxd1; sxd1 = t;
  }
  k_end_m<<<Rq/64,256,0,stream>>>(skip, ws, endB, out);
}

// Round 8
// 535.011 us; speedup vs baseline: 2.6155x; 1.1768x over previous
//
#include <hip/hip_runtime.h>
#include <math.h>

// Problem dims
#define Bq 4
#define Tq 64
#define Nq 256
#define Eq 128
#define Dq 64
#define Rq (Bq*Nq*Tq)      // 65536 rows (b,n,t)
#define ELEMS (Rq*Dq)      // 4194304

// ws offsets (in floats)
#define O_Q    0
#define O_K    65536
#define O_HD   73728
#define O_IDD  204800
#define O_IBD  205824
#define O_HG   206336
#define O_IDG  239104
#define O_IBG  239360
#define O_AN   239488      // bf16 now: 262144 elems = 131072 floats of space
#define O_AG   501632      // bf16 now: 65536 elems
#define O_WFT  567168      // MFMA weight-fragment area
#define O_BIG  632704
#define WS_FLOATS (O_BIG + 6*ELEMS)

// fragment sub-offsets (floats, relative to ws+O_WFT)
#define FR_FILT 0          // 3 x 2048
#define FR_GATE 6144       // 3 x 2048
#define FR_SKIP 12288      // 3 x 2048
#define FR_WFA  18432      // 2048
#define FR_WGA  20480      // 2048
#define FR_WBB  22528      // 2048 (WfB + WgB)
#define FR_WO   24576      // 4096 (K=128)
#define FR_WE   28672      // 2048
#define FR_CW0  30720      // 2048 convW[0]^T
#define FR_CW1  32768      // 2048 convW[1]^T
#define FR_CG0  34816      // 2048 convWg[0]^T
#define FR_CG1  36864      // 2048 convWg[1]^T

typedef __attribute__((ext_vector_type(8))) short bf16x8;
typedef __attribute__((ext_vector_type(4))) float f32x4;
#define MFMA16(a,b,c) __builtin_amdgcn_mfma_f32_16x16x32_bf16(a,b,c,0,0,0)

__device__ __forceinline__ float sigmoidf_(float x){ return 1.f/(1.f+expf(-x)); }

__device__ __forceinline__ unsigned short bf(float x){
  union{float f; unsigned u;} v; v.f=x;
  unsigned r=(v.u + 0x7FFFu + ((v.u>>16)&1u))>>16;
  return (unsigned short)r;
}
__device__ __forceinline__ float b2f(unsigned short u){
  union{unsigned u; float f;} v; v.u = ((unsigned)u)<<16; return v.f;
}
__device__ __forceinline__ bf16x8 cvt8(const float* p){
  float4 a=*(const float4*)p; float4 b=*(const float4*)(p+4);
  bf16x8 r;
  r[0]=bf(a.x); r[1]=bf(a.y); r[2]=bf(a.z); r[3]=bf(a.w);
  r[4]=bf(b.x); r[5]=bf(b.y); r[6]=bf(b.z); r[7]=bf(b.w);
  return r;
}

// ---------------- weight fragment precompute (once per launch) ----------------
__global__ __launch_bounds__(64) void k_wfrag(
    const float* __restrict__ filtW, const float* __restrict__ gateW,
    const float* __restrict__ skipW, const float* __restrict__ Wfuse,
    const float* __restrict__ Wgfuse, const float* __restrict__ outW,
    const float* __restrict__ endW, const float* __restrict__ convW,
    const float* __restrict__ convWg, float* __restrict__ ws){
  int job=blockIdx.x, l=threadIdx.x;
  const float* s1; const float* s2=nullptr; int stride=64, KC=2, tr=0; float* dst;
  float* fr = ws + O_WFT;
  if      (job<3){ s1=filtW+job*4096;     stride=64;  dst=fr+FR_FILT+job*2048; }
  else if (job<6){ s1=gateW+(job-3)*4096; stride=64;  dst=fr+FR_GATE+(job-3)*2048; }
  else if (job<9){ s1=skipW+(job-6)*4096; stride=64;  dst=fr+FR_SKIP+(job-6)*2048; }
  else if (job==9){  s1=Wfuse;            stride=128; dst=fr+FR_WFA; }
  else if (job==10){ s1=Wgfuse;           stride=128; dst=fr+FR_WGA; }
  else if (job==11){ s1=Wfuse+64; s2=Wgfuse+64; stride=128; dst=fr+FR_WBB; }
  else if (job==12){ s1=outW;             stride=128; KC=4; dst=fr+FR_WO; }
  else if (job==13){ s1=endW;             stride=64;  dst=fr+FR_WE; }
  else { int q=job-14; tr=1;
         s1 = (q<2) ? (convW + q*4096) : (convWg + (q-2)*4096);
         dst = fr + FR_CW0 + q*2048; }
  int m=l&15, g=l>>4;
  for (int dt=0; dt<4; ++dt) for (int kc=0; kc<KC; ++kc){
    unsigned short* d = (unsigned short*)(dst + ((size_t)(dt*KC+kc)*64 + l)*4);
    for (int i=0;i<8;i++){
      float v;
      if (tr) v = s1[(32*kc+8*g+i)*64 + (16*dt+m)];
      else {
        v = s1[(16*dt+m)*stride + 32*kc + 8*g + i];
        if (s2) v += s2[(16*dt+m)*stride + 32*kc + 8*g + i];
      }
      d[i] = bf(v);
    }
  }
}

// ---------------- phase 0 (fp32 except An/Ag outputs -> bf16) ----------------
__global__ __launch_bounds__(64) void k_q(const float* __restrict__ X,
    const float* __restrict__ nodeW, const float* __restrict__ nodeB,
    const float* __restrict__ Wq, float* __restrict__ Q) {
  int bn = blockIdx.x; int b = bn >> 8; int n = bn & 255;
  int tid = threadIdx.x;
  __shared__ float xcol[Tq];
  __shared__ float ee[Dq];
  xcol[tid] = X[(b*Tq + tid)*Nq + n];
  __syncthreads();
  float acc = 0.f;
  #pragma unroll 8
  for (int t=0;t<Tq;t++) acc += xcol[t]*nodeW[tid*Tq+t];
  ee[tid] = acc + nodeB[tid];
  __syncthreads();
  float q = 0.f;
  #pragma unroll 8
  for (int d=0; d<Dq; d++) q += ee[d]*Wq[tid*Dq+d];
  Q[bn*Dq+tid] = q;
}

__global__ __launch_bounds__(64) void k_k(const float* __restrict__ he,
    const float* __restrict__ Wk, float* __restrict__ K) {
  int e = blockIdx.x; int tid = threadIdx.x;
  __shared__ float hr[Dq];
  hr[tid] = he[e*Dq+tid];
  __syncthreads();
  float acc = 0.f;
  #pragma unroll 8
  for (int d=0; d<Dq; d++) acc += hr[d]*Wk[tid*Dq+d];
  K[e*Dq+tid] = acc;
}

__global__ __launch_bounds__(128) void k_h(const float* __restrict__ Q,
    const float* __restrict__ K, float* __restrict__ H, float* __restrict__ invDd) {
  int bn = blockIdx.x; int tid = threadIdx.x;
  __shared__ float qr[Dq];
  __shared__ float red[Eq];
  if (tid < Dq) qr[tid] = Q[bn*Dq+tid];
  __syncthreads();
  float s = 0.f;
  const float* kr = K + tid*Dq;
  #pragma unroll 8
  for (int d=0; d<Dq; d++) s += qr[d]*kr[d];
  s *= 0.125f;
  red[tid] = s; __syncthreads();
  for (int off=64; off>0; off>>=1){ if (tid<off) red[tid]=fmaxf(red[tid],red[tid+off]); __syncthreads(); }
  float mx = red[0]; __syncthreads();
  float e = expf(s-mx);
  red[tid] = e; __syncthreads();
  for (int off=64; off>0; off>>=1){ if (tid<off) red[tid]+=red[tid+off]; __syncthreads(); }
  float sm = red[0]; __syncthreads();
  float h = e/sm;
  H[bn*Eq+tid] = h;
  red[tid]=h; __syncthreads();
  for (int off=64; off>0; off>>=1){ if (tid<off) red[tid]+=red[tid+off]; __syncthreads(); }
  if (tid==0){ float dd = red[0]; invDd[bn] = dd>0.f ? 1.f/(dd+1e-8f) : 0.f; }
}

__global__ __launch_bounds__(256) void k_bd(const float* __restrict__ H,
    float* __restrict__ invBd) {
  int idx = blockIdx.x*256 + threadIdx.x;
  if (idx >= Bq*Eq) return;
  int b = idx >> 7; int e = idx & 127;
  float s=0.f;
  for (int n=0;n<Nq;n++) s += H[(b*Nq+n)*Eq + e];
  invBd[idx] = s>0.f ? 1.f/(s+1e-8f) : 0.f;
}

__global__ __launch_bounds__(128) void k_hgeo(const float* __restrict__ A,
    const float* __restrict__ Gl, float* __restrict__ Hg, float* __restrict__ invDg) {
  int n = blockIdx.x; int tid = threadIdx.x;
  __shared__ float ar[Nq];
  __shared__ float red[Eq];
  ar[tid] = A[n*Nq+tid]; ar[tid+128] = A[n*Nq+128+tid];
  __syncthreads();
  float s=0.f;
  #pragma unroll 4
  for (int k=0;k<Nq;k++) s += ar[k]*Gl[k*Eq+tid];
  Hg[n*Eq+tid] = s;
  red[tid]=s; __syncthreads();
  for (int off=64; off>0; off>>=1){ if (tid<off) red[tid]+=red[tid+off]; __syncthreads(); }
  if (tid==0){ float dg=red[0]; invDg[n] = dg>0.f ? 1.f/(dg+1e-8f):0.f; }
}

__global__ __launch_bounds__(128) void k_bg(const float* __restrict__ Hg,
    float* __restrict__ invBg){
  int e = threadIdx.x;
  float s=0.f;
  for (int n=0;n<Nq;n++) s += Hg[n*Eq+e];
  invBg[e] = s>0.f ? 1.f/(s+1e-8f) : 0.f;
}

__global__ __launch_bounds__(256) void k_anorm(const float* __restrict__ H,
    const float* __restrict__ invDd, const float* __restrict__ invBd,
    unsigned short* __restrict__ An) {
  int bid = blockIdx.x; int b = bid>>8; int i = bid&255; int j = threadIdx.x;
  __shared__ float hr[Eq];
  if (j < Eq) hr[j] = H[(b*Nq+i)*Eq+j] * invBd[b*Eq+j];
  __syncthreads();
  const float* hj = H + (b*Nq+j)*Eq;
  float s=0.f;
  #pragma unroll 8
  for (int e=0;e<Eq;e++) s += hr[e]*hj[e];
  An[(b*Nq+i)*Nq + j] = bf(invDd[b*Nq+i]*s);
}

__global__ __launch_bounds__(256) void k_ageo(const float* __restrict__ Hg,
    const float* __restrict__ invDg, const float* __restrict__ invBg,
    unsigned short* __restrict__ Ag) {
  int i = blockIdx.x; int j = threadIdx.x;
  __shared__ float hr[Eq];
  if (j<Eq) hr[j] = Hg[i*Eq+j]*invBg[j];
  __syncthreads();
  const float* hj = Hg + j*Eq;
  float s=0.f;
  #pragma unroll 8
  for (int e=0;e<Eq;e++) s+=hr[e]*hj[e];
  Ag[i*Nq+j] = bf(invDg[i]*s);
}

// ---------------- start: x(bf16) = X*start_W + start_b ; skip(fp32) = same ----------------
__global__ __launch_bounds__(256) void k_start(const float* __restrict__ X,
    const float* __restrict__ sW, const float* __restrict__ sB,
    unsigned short* __restrict__ x, float* __restrict__ skip) {
  int idx4 = blockIdx.x*256+threadIdx.x;
  int base = idx4*4;
  int row = base>>6, d0 = base&63;
  int b = row>>14, n = (row>>6)&255, t = row&63;
  float xv = X[(b*Tq+t)*Nq + n];
  float4 w = *(const float4*)&sW[d0];
  float4 bb = *(const float4*)&sB[d0];
  float4 v = make_float4(xv*w.x+bb.x, xv*w.y+bb.y, xv*w.z+bb.z, xv*w.w+bb.w);
  *(ushort4*)&x[base] = make_ushort4(bf(v.x),bf(v.y),bf(v.z),bf(v.w));
  *(float4*)&skip[base] = v;
}

// ---------------- MFMA row-family (bf16 I/O) ----------------
__global__ __launch_bounds__(256) void k_fg_m(
    const unsigned short* __restrict__ x, const float* __restrict__ ws,
    const float* __restrict__ fb, const float* __restrict__ gb,
    const float* __restrict__ sb, int layer,
    unsigned short* __restrict__ xf, float* __restrict__ skip,
    unsigned short* __restrict__ xw, unsigned short* __restrict__ xwg){
  __shared__ unsigned short smem[4][16*72];
  int tid=threadIdx.x, w=tid>>6, l=tid&63, m=l&15, g=l>>4;
  const bf16x8* FF=(const bf16x8*)(ws+O_WFT+FR_FILT)+(size_t)layer*512;
  const bf16x8* FG=(const bf16x8*)(ws+O_WFT+FR_GATE)+(size_t)layer*512;
  const bf16x8* FS=(const bf16x8*)(ws+O_WFT+FR_SKIP)+(size_t)layer*512;
  const bf16x8* CW0=(const bf16x8*)(ws+O_WFT+FR_CW0);
  const bf16x8* CG0=(const bf16x8*)(ws+O_WFT+FR_CG0);
  int r = blockIdx.x*64 + w*16 + m;
  const unsigned short* xr = x + (size_t)r*64;
  bf16x8 xb0=*(const bf16x8*)(xr+8*g), xb1=*(const bf16x8*)(xr+32+8*g);
  f32x4 z; z[0]=0.f; z[1]=0.f; z[2]=0.f; z[3]=0.f;
  #pragma unroll
  for(int dt=0;dt<4;dt++){
    f32x4 aF=MFMA16(FF[(dt*2+1)*64+l],xb1,MFMA16(FF[(dt*2+0)*64+l],xb0,z));
    f32x4 aG=MFMA16(FG[(dt*2+1)*64+l],xb1,MFMA16(FG[(dt*2+0)*64+l],xb0,z));
    float4 fb4=*(const float4*)&fb[16*dt+4*g];
    float4 gb4=*(const float4*)&gb[16*dt+4*g];
    float y0=tanhf(aF[0]+fb4.x)*sigmoidf_(aG[0]+gb4.x);
    float y1=tanhf(aF[1]+fb4.y)*sigmoidf_(aG[1]+gb4.y);
    float y2=tanhf(aF[2]+fb4.z)*sigmoidf_(aG[2]+gb4.z);
    float y3=tanhf(aF[3]+fb4.w)*sigmoidf_(aG[3]+gb4.w);
    ushort4 yy=make_ushort4(bf(y0),bf(y1),bf(y2),bf(y3));
    *(ushort4*)&xf[(size_t)r*64+16*dt+4*g]=yy;
    *(ushort4*)&smem[w][m*72+16*dt+4*g]=yy;
  }
  __syncthreads();
  bf16x8 yb0=*(const bf16x8*)&smem[w][m*72+8*g];
  bf16x8 yb1=*(const bf16x8*)&smem[w][m*72+32+8*g];
  #pragma unroll
  for(int dt=0;dt<4;dt++){
    f32x4 aS=MFMA16(FS[(dt*2+1)*64+l],yb1,MFMA16(FS[(dt*2+0)*64+l],yb0,z));
    float4 sb4=*(const float4*)&sb[16*dt+4*g];
    size_t o=(size_t)r*64+16*dt+4*g;
    float4 sv=*(float4*)&skip[o];
    sv.x+=aS[0]+sb4.x; sv.y+=aS[1]+sb4.y; sv.z+=aS[2]+sb4.z; sv.w+=aS[3]+sb4.w;
    *(float4*)&skip[o]=sv;
  }
  #pragma unroll
  for(int dt=0;dt<4;dt++){
    f32x4 aW=MFMA16(CW0[(dt*2+1)*64+l],yb1,MFMA16(CW0[(dt*2+0)*64+l],yb0,z));
    *(ushort4*)&xw[(size_t)r*64+16*dt+4*g]=make_ushort4(bf(aW[0]),bf(aW[1]),bf(aW[2]),bf(aW[3]));
    f32x4 aH=MFMA16(CG0[(dt*2+1)*64+l],yb1,MFMA16(CG0[(dt*2+0)*64+l],yb0,z));
    *(ushort4*)&xwg[(size_t)r*64+16*dt+4*g]=make_ushort4(bf(aH[0]),bf(aH[1]),bf(aH[2]),bf(aH[3]));
  }
}

// combine: xd <- V*xd + (1-V)*xg ; if ep: wA = xd@convW[1], wB = xg@convWg[1]
__global__ __launch_bounds__(256) void k_comb_m(
    unsigned short* __restrict__ xd, const unsigned short* __restrict__ xg,
    const unsigned short* __restrict__ xs, const float* __restrict__ ws,
    int ep, unsigned short* __restrict__ wA, unsigned short* __restrict__ wB){
  int tid=threadIdx.x, w=tid>>6, l=tid&63, m=l&15, g=l>>4;
  const bf16x8* FA=(const bf16x8*)(ws+O_WFT+FR_WFA);
  const bf16x8* GA=(const bf16x8*)(ws+O_WFT+FR_WGA);
  const bf16x8* BB=(const bf16x8*)(ws+O_WFT+FR_WBB);
  int r=blockIdx.x*64+w*16+m;
  const unsigned short* pd=xd+(size_t)r*64;
  const unsigned short* pg=xg+(size_t)r*64;
  const unsigned short* p0=xs+(size_t)r*64;
  bf16x8 d0=*(const bf16x8*)(pd+8*g), d1=*(const bf16x8*)(pd+32+8*g);
  bf16x8 g0=*(const bf16x8*)(pg+8*g), g1=*(const bf16x8*)(pg+32+8*g);
  bf16x8 s0=*(const bf16x8*)(p0+8*g), s1=*(const bf16x8*)(p0+32+8*g);
  f32x4 z; z[0]=0.f; z[1]=0.f; z[2]=0.f; z[3]=0.f;
  #pragma unroll
  for(int dt=0;dt<4;dt++){
    f32x4 a=MFMA16(FA[(dt*2+0)*64+l],d0,z);
    a=MFMA16(FA[(dt*2+1)*64+l],d1,a);
    a=MFMA16(GA[(dt*2+0)*64+l],g0,a);
    a=MFMA16(GA[(dt*2+1)*64+l],g1,a);
    a=MFMA16(BB[(dt*2+0)*64+l],s0,a);
    a=MFMA16(BB[(dt*2+1)*64+l],s1,a);
    size_t o=(size_t)r*64+16*dt+4*g;
    ushort4 dv4=*(const ushort4*)&xd[o];
    ushort4 gv4=*(const ushort4*)&xg[o];
    float V0=sigmoidf_(a[0]), V1=sigmoidf_(a[1]), V2=sigmoidf_(a[2]), V3=sigmoidf_(a[3]);
    float o0=V0*b2f(dv4.x)+(1.f-V0)*b2f(gv4.x);
    float o1=V1*b2f(dv4.y)+(1.f-V1)*b2f(gv4.y);
    float o2=V2*b2f(dv4.z)+(1.f-V2)*b2f(gv4.z);
    float o3=V3*b2f(dv4.w)+(1.f-V3)*b2f(gv4.w);
    *(ushort4*)&xd[o]=make_ushort4(bf(o0),bf(o1),bf(o2),bf(o3));
  }
  if (ep){
    const bf16x8* CW1=(const bf16x8*)(ws+O_WFT+FR_CW1);
    const bf16x8* CG1=(const bf16x8*)(ws+O_WFT+FR_CG1);
    #pragma unroll
    for(int dt=0;dt<4;dt++){
      f32x4 a1=MFMA16(CW1[(dt*2+1)*64+l],d1,MFMA16(CW1[(dt*2+0)*64+l],d0,z));
      *(ushort4*)&wA[(size_t)r*64+16*dt+4*g]=make_ushort4(bf(a1[0]),bf(a1[1]),bf(a1[2]),bf(a1[3]));
      f32x4 a2=MFMA16(CG1[(dt*2+1)*64+l],g1,MFMA16(CG1[(dt*2+0)*64+l],g0,z));
      *(ushort4*)&wB[(size_t)r*64+16*dt+4*g]=make_ushort4(bf(a2[0]),bf(a2[1]),bf(a2[2]),bf(a2[3]));
    }
  }
}

__global__ __launch_bounds__(256) void k_out_m(
    const unsigned short* __restrict__ o0, const unsigned short* __restrict__ o1,
    const float* __restrict__ ws, const float* __restrict__ ob,
    const float* __restrict__ gamma, const float* __restrict__ beta,
    unsigned short* __restrict__ xn){
  int tid=threadIdx.x, w=tid>>6, l=tid&63, m=l&15, g=l>>4;
  const bf16x8* WO=(const bf16x8*)(ws+O_WFT+FR_WO);
  int r=blockIdx.x*64+w*16+m;
  const unsigned short* a0=o0+(size_t)r*64;
  const unsigned short* a1=o1+(size_t)r*64;
  bf16x8 b0=*(const bf16x8*)(a0+8*g), b1=*(const bf16x8*)(a0+32+8*g);
  bf16x8 b2=*(const bf16x8*)(a1+8*g), b3=*(const bf16x8*)(a1+32+8*g);
  f32x4 z; z[0]=0.f; z[1]=0.f; z[2]=0.f; z[3]=0.f;
  float y[4][4]; float s=0.f;
  #pragma unroll
  for(int dt=0;dt<4;dt++){
    f32x4 a=MFMA16(WO[(dt*4+0)*64+l],b0,z);
    a=MFMA16(WO[(dt*4+1)*64+l],b1,a);
    a=MFMA16(WO[(dt*4+2)*64+l],b2,a);
    a=MFMA16(WO[(dt*4+3)*64+l],b3,a);
    float4 bb=*(const float4*)&ob[16*dt+4*g];
    y[dt][0]=a[0]+bb.x; y[dt][1]=a[1]+bb.y; y[dt][2]=a[2]+bb.z; y[dt][3]=a[3]+bb.w;
    s+=y[dt][0]+y[dt][1]+y[dt][2]+y[dt][3];
  }
  s+=__shfl_xor(s,16); s+=__shfl_xor(s,32);
  float mean=s*(1.f/64.f);
  float q=0.f;
  #pragma unroll
  for(int dt=0;dt<4;dt++){
    #pragma unroll
    for(int j=0;j<4;j++){ float e=y[dt][j]-mean; q+=e*e; }
  }
  q+=__shfl_xor(q,16); q+=__shfl_xor(q,32);
  float rstd=rsqrtf(q*(1.f/64.f)+1e-5f);
  #pragma unroll
  for(int dt=0;dt<4;dt++){
    float4 g4=*(const float4*)&gamma[16*dt+4*g];
    float4 be4=*(const float4*)&beta[16*dt+4*g];
    *(ushort4*)&xn[(size_t)r*64+16*dt+4*g]=make_ushort4(
      bf((y[dt][0]-mean)*rstd*g4.x+be4.x),
      bf((y[dt][1]-mean)*rstd*g4.y+be4.y),
      bf((y[dt][2]-mean)*rstd*g4.z+be4.z),
      bf((y[dt][3]-mean)*rstd*g4.w+be4.w));
  }
}

__global__ __launch_bounds__(256) void k_end_m(
    const float* __restrict__ skip, const float* __restrict__ ws,
    const float* __restrict__ eb, float* __restrict__ out){
  int tid=threadIdx.x, w=tid>>6, l=tid&63, m=l&15, g=l>>4;
  const bf16x8* WE=(const bf16x8*)(ws+O_WFT+FR_WE);
  int r=blockIdx.x*64+w*16+m;
  const float* sr=skip+(size_t)r*64;
  float t0[8], t1[8];
  {
    float4 a=*(const float4*)(sr+8*g), b=*(const float4*)(sr+8*g+4);
    t0[0]=fmaxf(a.x,0.f); t0[1]=fmaxf(a.y,0.f); t0[2]=fmaxf(a.z,0.f); t0[3]=fmaxf(a.w,0.f);
    t0[4]=fmaxf(b.x,0.f); t0[5]=fmaxf(b.y,0.f); t0[6]=fmaxf(b.z,0.f); t0[7]=fmaxf(b.w,0.f);
    float4 c=*(const float4*)(sr+32+8*g), d=*(const float4*)(sr+32+8*g+4);
    t1[0]=fmaxf(c.x,0.f); t1[1]=fmaxf(c.y,0.f); t1[2]=fmaxf(c.z,0.f); t1[3]=fmaxf(c.w,0.f);
    t1[4]=fmaxf(d.x,0.f); t1[5]=fmaxf(d.y,0.f); t1[6]=fmaxf(d.z,0.f); t1[7]=fmaxf(d.w,0.f);
  }
  bf16x8 s0,s1;
  #pragma unroll
  for(int i=0;i<8;i++){ s0[i]=(short)bf(t0[i]); s1[i]=(short)bf(t1[i]); }
  f32x4 z; z[0]=0.f; z[1]=0.f; z[2]=0.f; z[3]=0.f;
  int b_=r>>14, n_=(r>>6)&255, t_=r&63;
  size_t obase=((size_t)(b_*Tq+t_)*Nq+n_)*64;
  #pragma unroll
  for(int dt=0;dt<4;dt++){
    f32x4 a=MFMA16(WE[(dt*2+1)*64+l],s1,MFMA16(WE[(dt*2+0)*64+l],s0,z));
    float4 bb=*(const float4*)&eb[16*dt+4*g];
    *(float4*)&out[obase+16*dt+4*g]=make_float4(a[0]+bb.x,a[1]+bb.y,a[2]+bb.z,a[3]+bb.w);
  }
}

// ---------------- spatial: out = Adj(256x256) @ in, all-bf16 ----------------
__global__ __launch_bounds__(256) void k_adj_m(const unsigned short* __restrict__ Adj,
    int adjStride, const unsigned short* __restrict__ in,
    unsigned short* __restrict__ out){
  __shared__ unsigned short ldsT[64*264];   // 33792 B
  int tid=threadIdx.x, w=tid>>6, l=tid&63, m=l&15, g=l>>4;
  int t0 = blockIdx.x & 63, mc=(blockIdx.x>>6)&3, b = blockIdx.x>>8;
  const unsigned short* Ar = Adj + (size_t)b*adjStride + (size_t)(mc*64 + w*16 + m)*256;
  bf16x8 afr[8];
  #pragma unroll
  for (int kc=0;kc<8;kc++) afr[kc] = *(const bf16x8*)(Ar + kc*32 + g*8);
  // stage in-tile transposed (pure short shuffle, no cvt)
  int dq=(tid&15)*4, ng=(tid>>4)*4;
  #pragma unroll
  for (int iter=0; iter<4; ++iter){
    int n0 = iter*64 + ng;
    const unsigned short* base = in + (((size_t)b*Nq + n0)*Tq + t0)*Dq + dq;
    ushort4 v0 = *(const ushort4*)(base);
    ushort4 v1 = *(const ushort4*)(base + 4096);
    ushort4 v2 = *(const ushort4*)(base + 8192);
    ushort4 v3 = *(const ushort4*)(base + 12288);
    *(ushort4*)&ldsT[(dq+0)*264 + n0] = make_ushort4(v0.x,v1.x,v2.x,v3.x);
    *(ushort4*)&ldsT[(dq+1)*264 + n0] = make_ushort4(v0.y,v1.y,v2.y,v3.y);
    *(ushort4*)&ldsT[(dq+2)*264 + n0] = make_ushort4(v0.z,v1.z,v2.z,v3.z);
    *(ushort4*)&ldsT[(dq+3)*264 + n0] = make_ushort4(v0.w,v1.w,v2.w,v3.w);
  }
  __syncthreads();
  f32x4 z; z[0]=0.f; z[1]=0.f; z[2]=0.f; z[3]=0.f;
  f32x4 acc[4] = {z,z,z,z};
  #pragma unroll
  for (int kc=0;kc<8;kc++){
    #pragma unroll
    for (int ct=0;ct<4;ct++){
      bf16x8 bfr = *(const bf16x8*)&ldsT[(ct*16+m)*264 + kc*32 + g*8];
      acc[ct]=MFMA16(afr[kc], bfr, acc[ct]);
    }
  }
  // lane holds out[M = mc*64+w*16+4g+j][d = ct*16+m]
  size_t ob = (((size_t)b*Nq + mc*64 + w*16 + 4*g)*Tq + t0)*Dq;
  #pragma unroll
  for (int ct=0;ct<4;ct++){
    #pragma unroll
    for (int j=0;j<4;j++){
      out[ob + (size_t)j*Tq*Dq + ct*16 + m] = bf(acc[ct][j]);
    }
  }
}

extern "C" void kernel_launch(void* const* d_in, const int* in_sizes, int n_in,
                              void* d_out, int out_size, void* d_ws, size_t ws_size,
                              hipStream_t stream) {
  const float* X    = (const float*)d_in[0];
  const float* A    = (const float*)d_in[1];
  const float* he   = (const float*)d_in[2];
  const float* Gl   = (const float*)d_in[3];
  const float* Wq   = (const float*)d_in[4];
  const float* Wk   = (const float*)d_in[5];
  const float* nodeW= (const float*)d_in[6];
  const float* nodeB= (const float*)d_in[7];
  const float* sW   = (const float*)d_in[8];
  const float* sB   = (const float*)d_in[9];
  const float* filtW= (const float*)d_in[10];
  const float* filtB= (const float*)d_in[11];
  const float* gateW= (const float*)d_in[12];
  const float* gateB= (const float*)d_in[13];
  const float* skipW= (const float*)d_in[14];
  const float* skipB= (const float*)d_in[15];
  const float* convW= (const float*)d_in[16];
  const float* convWg=(const float*)d_in[17];
  const float* Wfuse= (const float*)d_in[18];
  const float* Wgfuse=(const float*)d_in[19];
  const float* outW = (const float*)d_in[20];
  const float* outB = (const float*)d_in[21];
  const float* gamma= (const float*)d_in[22];
  const float* beta = (const float*)d_in[23];
  const float* endW = (const float*)d_in[24];
  const float* endB = (const float*)d_in[25];
  float* ws  = (float*)d_ws;
  float* out = (float*)d_out;
  if (ws_size < (size_t)WS_FLOATS*sizeof(float)) return;

  float* Qb = ws+O_Q;  float* Kb = ws+O_K;  float* Hd = ws+O_HD;
  float* iDd= ws+O_IDD; float* iBd= ws+O_IBD;
  float* Hg = ws+O_HG; float* iDg= ws+O_IDG; float* iBg= ws+O_IBG;
  unsigned short* An = (unsigned short*)(ws+O_AN);
  unsigned short* Ag = (unsigned short*)(ws+O_AG);
  float* big= ws+O_BIG;
  // slots: each ELEMS floats; bf16 tensors use first half of their slot
  float* skip = big + (size_t)2*ELEMS;            // fp32, persistent
  unsigned short* sx   = (unsigned short*)(big);
  unsigned short* sxf  = (unsigned short*)(big + (size_t)1*ELEMS);
  unsigned short* sw0  = (unsigned short*)(big + (size_t)3*ELEMS);
  unsigned short* swg0 = (unsigned short*)(big + (size_t)4*ELEMS);
  unsigned short* sxd1 = (unsigned short*)(big + (size_t)5*ELEMS);

  k_wfrag<<<18,64,0,stream>>>(filtW,gateW,skipW,Wfuse,Wgfuse,outW,endW,convW,convWg,ws);
  k_q<<<Bq*Nq,64,0,stream>>>(X,nodeW,nodeB,Wq,Qb);
  k_k<<<Eq,64,0,stream>>>(he,Wk,Kb);
  k_h<<<Bq*Nq,128,0,stream>>>(Qb,Kb,Hd,iDd);
  k_bd<<<2,256,0,stream>>>(Hd,iBd);
  k_hgeo<<<Nq,128,0,stream>>>(A,Gl,Hg,iDg);
  k_bg<<<1,128,0,stream>>>(Hg,iBg);
  k_anorm<<<Bq*Nq,256,0,stream>>>(Hd,iDd,iBd,An);
  k_ageo<<<Nq,256,0,stream>>>(Hg,iDg,iBg,Ag);
  k_start<<<ELEMS/1024,256,0,stream>>>(X,sW,sB,sx,skip);

  for (int i=0;i<3;i++){
    k_fg_m<<<Rq/64,256,0,stream>>>(sx, ws, filtB+i*64, gateB+i*64, skipB+i*64, i,
                                   sxf, skip, sw0, swg0);
    k_adj_m<<<1024,256,0,stream>>>(An, Nq*Nq, sw0, sxd1);        // xd1
    k_adj_m<<<1024,256,0,stream>>>(Ag, 0,     swg0, sw0);        // xg1
    k_comb_m<<<Rq/64,256,0,stream>>>(sxd1, sw0, sxf, ws, 1, sx, swg0);
    k_adj_m<<<1024,256,0,stream>>>(An, Nq*Nq, sx,  sw0);         // xd2
    k_adj_m<<<1024,256,0,stream>>>(Ag, 0,     swg0, sx);         // xg2
    k_comb_m<<<Rq/64,256,0,stream>>>(sw0, sx, sxf, ws, 0, nullptr, nullptr);
    k_out_m<<<Rq/64,256,0,stream>>>(sxd1, sw0, ws, outB, gamma, beta, swg0);
    unsigned short* t = sx; sx = swg0; swg0 = sxd1; sxd1 = t;
  }
  k_end_m<<<Rq/64,256,0,stream>>>(skip, ws, endB, out);
}

// Round 11
// 409.572 us; speedup vs baseline: 3.4165x; 1.3063x over previous
//
#include <hip/hip_runtime.h>
#include <math.h>

// Problem dims
#define Bq 4
#define Tq 64
#define Nq 256
#define Eq 128
#define Dq 64
#define Rq (Bq*Nq*Tq)      // 65536 rows (b,n,t)
#define ELEMS (Rq*Dq)      // 4194304

// ws offsets (in floats)
#define O_Q    0
#define O_K    65536
#define O_HD   73728
#define O_IDD  204800
#define O_IBD  205824
#define O_HG   206336
#define O_IDG  239104
#define O_IBG  239360
#define O_AN   239488      // bf16: 262144 elems
#define O_AG   501632      // bf16: 65536 elems
#define O_WFT  567168      // MFMA weight-fragment area
#define O_BIG  632704
#define WS_FLOATS (O_BIG + 6*ELEMS)

// fragment sub-offsets (floats, relative to ws+O_WFT)
#define FR_FILT 0          // 3 x 2048
#define FR_GATE 6144       // 3 x 2048
#define FR_SKIP 12288      // 3 x 2048
#define FR_WFA  18432      // 2048
#define FR_WGA  20480      // 2048
#define FR_WBB  22528      // 2048 (WfB + WgB)
#define FR_WO   24576      // 4096 (K=128)
#define FR_WE   28672      // 2048
#define FR_CW0  30720      // 2048 convW[0]^T
#define FR_CW1  32768      // 2048 convW[1]^T
#define FR_CG0  34816      // 2048 convWg[0]^T
#define FR_CG1  36864      // 2048 convWg[1]^T

typedef __attribute__((ext_vector_type(8))) short bf16x8;
typedef __attribute__((ext_vector_type(4))) float f32x4;
#define MFMA16(a,b,c) __builtin_amdgcn_mfma_f32_16x16x32_bf16(a,b,c,0,0,0)

__device__ __forceinline__ float sigmoidf_(float x){ return 1.f/(1.f+expf(-x)); }

__device__ __forceinline__ unsigned short bf(float x){
  union{float f; unsigned u;} v; v.f=x;
  unsigned r=(v.u + 0x7FFFu + ((v.u>>16)&1u))>>16;
  return (unsigned short)r;
}
__device__ __forceinline__ float b2f(unsigned short u){
  union{unsigned u; float f;} v; v.u = ((unsigned)u)<<16; return v.f;
}

// ---------------- weight fragment precompute ----------------
__global__ __launch_bounds__(64) void k_wfrag(
    const float* __restrict__ filtW, const float* __restrict__ gateW,
    const float* __restrict__ skipW, const float* __restrict__ Wfuse,
    const float* __restrict__ Wgfuse, const float* __restrict__ outW,
    const float* __restrict__ endW, const float* __restrict__ convW,
    const float* __restrict__ convWg, float* __restrict__ ws){
  int job=blockIdx.x, l=threadIdx.x;
  const float* s1; const float* s2=nullptr; int stride=64, KC=2, tr=0; float* dst;
  float* fr = ws + O_WFT;
  if      (job<3){ s1=filtW+job*4096;     stride=64;  dst=fr+FR_FILT+job*2048; }
  else if (job<6){ s1=gateW+(job-3)*4096; stride=64;  dst=fr+FR_GATE+(job-3)*2048; }
  else if (job<9){ s1=skipW+(job-6)*4096; stride=64;  dst=fr+FR_SKIP+(job-6)*2048; }
  else if (job==9){  s1=Wfuse;            stride=128; dst=fr+FR_WFA; }
  else if (job==10){ s1=Wgfuse;           stride=128; dst=fr+FR_WGA; }
  else if (job==11){ s1=Wfuse+64; s2=Wgfuse+64; stride=128; dst=fr+FR_WBB; }
  else if (job==12){ s1=outW;             stride=128; KC=4; dst=fr+FR_WO; }
  else if (job==13){ s1=endW;             stride=64;  dst=fr+FR_WE; }
  else { int q=job-14; tr=1;
         s1 = (q<2) ? (convW + q*4096) : (convWg + (q-2)*4096);
         dst = fr + FR_CW0 + q*2048; }
  int m=l&15, g=l>>4;
  for (int dt=0; dt<4; ++dt) for (int kc=0; kc<KC; ++kc){
    unsigned short* d = (unsigned short*)(dst + ((size_t)(dt*KC+kc)*64 + l)*4);
    for (int i=0;i<8;i++){
      float v;
      if (tr) v = s1[(32*kc+8*g+i)*64 + (16*dt+m)];
      else {
        v = s1[(16*dt+m)*stride + 32*kc + 8*g + i];
        if (s2) v += s2[(16*dt+m)*stride + 32*kc + 8*g + i];
      }
      d[i] = bf(v);
    }
  }
}

// ---------------- phase 0 (merged) ----------------
// blocks [0,1024): Q rows; [1024,1152): K rows
__global__ __launch_bounds__(64) void k_qk(const float* __restrict__ X,
    const float* __restrict__ nodeW, const float* __restrict__ nodeB,
    const float* __restrict__ Wq, const float* __restrict__ he,
    const float* __restrict__ Wk, float* __restrict__ Q, float* __restrict__ K) {
  int tid = threadIdx.x;
  if (blockIdx.x < 1024){
    int bn = blockIdx.x; int b = bn >> 8; int n = bn & 255;
    __shared__ float xcol[Tq];
    __shared__ float ee[Dq];
    xcol[tid] = X[(b*Tq + tid)*Nq + n];
    __syncthreads();
    float acc = 0.f;
    #pragma unroll 8
    for (int t=0;t<Tq;t++) acc += xcol[t]*nodeW[tid*Tq+t];
    ee[tid] = acc + nodeB[tid];
    __syncthreads();
    float q = 0.f;
    #pragma unroll 8
    for (int d=0; d<Dq; d++) q += ee[d]*Wq[tid*Dq+d];
    Q[bn*Dq+tid] = q;
  } else {
    int e = blockIdx.x - 1024;
    __shared__ float hr[Dq];
    hr[tid] = he[e*Dq+tid];
    __syncthreads();
    float acc = 0.f;
    #pragma unroll 8
    for (int d=0; d<Dq; d++) acc += hr[d]*Wk[tid*Dq+d];
    K[e*Dq+tid] = acc;
  }
}

__global__ __launch_bounds__(128) void k_h(const float* __restrict__ Q,
    const float* __restrict__ K, float* __restrict__ H, float* __restrict__ invDd) {
  int bn = blockIdx.x; int tid = threadIdx.x;
  __shared__ float qr[Dq];
  __shared__ float red[Eq];
  if (tid < Dq) qr[tid] = Q[bn*Dq+tid];
  __syncthreads();
  float s = 0.f;
  const float* kr = K + tid*Dq;
  #pragma unroll 8
  for (int d=0; d<Dq; d++) s += qr[d]*kr[d];
  s *= 0.125f;
  red[tid] = s; __syncthreads();
  for (int off=64; off>0; off>>=1){ if (tid<off) red[tid]=fmaxf(red[tid],red[tid+off]); __syncthreads(); }
  float mx = red[0]; __syncthreads();
  float e = expf(s-mx);
  red[tid] = e; __syncthreads();
  for (int off=64; off>0; off>>=1){ if (tid<off) red[tid]+=red[tid+off]; __syncthreads(); }
  float sm = red[0]; __syncthreads();
  float h = e/sm;
  H[bn*Eq+tid] = h;
  red[tid]=h; __syncthreads();
  for (int off=64; off>0; off>>=1){ if (tid<off) red[tid]+=red[tid+off]; __syncthreads(); }
  if (tid==0){ float dd = red[0]; invDd[bn] = dd>0.f ? 1.f/(dd+1e-8f) : 0.f; }
}

__global__ __launch_bounds__(128) void k_hgeo(const float* __restrict__ A,
    const float* __restrict__ Gl, float* __restrict__ Hg, float* __restrict__ invDg) {
  int n = blockIdx.x; int tid = threadIdx.x;
  __shared__ float ar[Nq];
  __shared__ float red[Eq];
  ar[tid] = A[n*Nq+tid]; ar[tid+128] = A[n*Nq+128+tid];
  __syncthreads();
  float s=0.f;
  #pragma unroll 4
  for (int k=0;k<Nq;k++) s += ar[k]*Gl[k*Eq+tid];
  Hg[n*Eq+tid] = s;
  red[tid]=s; __syncthreads();
  for (int off=64; off>0; off>>=1){ if (tid<off) red[tid]+=red[tid+off]; __syncthreads(); }
  if (tid==0){ float dg=red[0]; invDg[n] = dg>0.f ? 1.f/(dg+1e-8f):0.f; }
}

// blocks 0,1: invBd; block 2 (threads<128): invBg
__global__ __launch_bounds__(256) void k_bdg(const float* __restrict__ H,
    const float* __restrict__ Hg, float* __restrict__ invBd, float* __restrict__ invBg) {
  if (blockIdx.x < 2){
    int idx = blockIdx.x*256 + threadIdx.x;
    int b = idx >> 7; int e = idx & 127;
    float s=0.f;
    for (int n=0;n<Nq;n++) s += H[(b*Nq+n)*Eq + e];
    invBd[idx] = s>0.f ? 1.f/(s+1e-8f) : 0.f;
  } else if (threadIdx.x < 128){
    int e = threadIdx.x;
    float s=0.f;
    for (int n=0;n<Nq;n++) s += Hg[n*Eq+e];
    invBg[e] = s>0.f ? 1.f/(s+1e-8f) : 0.f;
  }
}

// blocks [0,1024): An; [1024,1280): Ag
__global__ __launch_bounds__(256) void k_norm2(const float* __restrict__ H,
    const float* __restrict__ invDd, const float* __restrict__ invBd,
    const float* __restrict__ Hg, const float* __restrict__ invDg,
    const float* __restrict__ invBg, unsigned short* __restrict__ An,
    unsigned short* __restrict__ Ag) {
  __shared__ float hr[Eq];
  int j = threadIdx.x;
  if (blockIdx.x < 1024){
    int bid = blockIdx.x; int b = bid>>8; int i = bid&255;
    if (j < Eq) hr[j] = H[(b*Nq+i)*Eq+j] * invBd[b*Eq+j];
    __syncthreads();
    const float* hj = H + (b*Nq+j)*Eq;
    float s=0.f;
    #pragma unroll 8
    for (int e=0;e<Eq;e++) s += hr[e]*hj[e];
    An[(b*Nq+i)*Nq + j] = bf(invDd[b*Nq+i]*s);
  } else {
    int i = blockIdx.x - 1024;
    if (j<Eq) hr[j] = Hg[i*Eq+j]*invBg[j];
    __syncthreads();
    const float* hj = Hg + j*Eq;
    float s=0.f;
    #pragma unroll 8
    for (int e=0;e<Eq;e++) s+=hr[e]*hj[e];
    Ag[i*Nq+j] = bf(invDg[i]*s);
  }
}

// ---------------- start ----------------
__global__ __launch_bounds__(256) void k_start(const float* __restrict__ X,
    const float* __restrict__ sW, const float* __restrict__ sB,
    unsigned short* __restrict__ x, float* __restrict__ skip) {
  int idx4 = blockIdx.x*256+threadIdx.x;
  int base = idx4*4;
  int row = base>>6, d0 = base&63;
  int b = row>>14, n = (row>>6)&255, t = row&63;
  float xv = X[(b*Tq+t)*Nq + n];
  float4 w = *(const float4*)&sW[d0];
  float4 bb = *(const float4*)&sB[d0];
  float4 v = make_float4(xv*w.x+bb.x, xv*w.y+bb.y, xv*w.z+bb.z, xv*w.w+bb.w);
  *(ushort4*)&x[base] = make_ushort4(bf(v.x),bf(v.y),bf(v.z),bf(v.w));
  *(float4*)&skip[base] = v;
}

// ---------------- fg: xf=tanh*sig; skip+=; if full: xw=xf@CW0, xwg=xf@CG0 ----------------
__global__ __launch_bounds__(256) void k_fg_m(
    const unsigned short* __restrict__ x, const float* __restrict__ ws,
    const float* __restrict__ fb, const float* __restrict__ gb,
    const float* __restrict__ sb, int layer, int full,
    unsigned short* __restrict__ xf, float* __restrict__ skip,
    unsigned short* __restrict__ xw, unsigned short* __restrict__ xwg){
  __shared__ unsigned short smem[4][16*72];
  int tid=threadIdx.x, w=tid>>6, l=tid&63, m=l&15, g=l>>4;
  const bf16x8* FF=(const bf16x8*)(ws+O_WFT+FR_FILT)+(size_t)layer*512;
  const bf16x8* FG=(const bf16x8*)(ws+O_WFT+FR_GATE)+(size_t)layer*512;
  const bf16x8* FS=(const bf16x8*)(ws+O_WFT+FR_SKIP)+(size_t)layer*512;
  const bf16x8* CW0=(const bf16x8*)(ws+O_WFT+FR_CW0);
  const bf16x8* CG0=(const bf16x8*)(ws+O_WFT+FR_CG0);
  int r = blockIdx.x*64 + w*16 + m;
  const unsigned short* xr = x + (size_t)r*64;
  bf16x8 xb0=*(const bf16x8*)(xr+8*g), xb1=*(const bf16x8*)(xr+32+8*g);
  f32x4 z; z[0]=0.f; z[1]=0.f; z[2]=0.f; z[3]=0.f;
  #pragma unroll
  for(int dt=0;dt<4;dt++){
    f32x4 aF=MFMA16(FF[(dt*2+1)*64+l],xb1,MFMA16(FF[(dt*2+0)*64+l],xb0,z));
    f32x4 aG=MFMA16(FG[(dt*2+1)*64+l],xb1,MFMA16(FG[(dt*2+0)*64+l],xb0,z));
    float4 fb4=*(const float4*)&fb[16*dt+4*g];
    float4 gb4=*(const float4*)&gb[16*dt+4*g];
    float y0=tanhf(aF[0]+fb4.x)*sigmoidf_(aG[0]+gb4.x);
    float y1=tanhf(aF[1]+fb4.y)*sigmoidf_(aG[1]+gb4.y);
    float y2=tanhf(aF[2]+fb4.z)*sigmoidf_(aG[2]+gb4.z);
    float y3=tanhf(aF[3]+fb4.w)*sigmoidf_(aG[3]+gb4.w);
    ushort4 yy=make_ushort4(bf(y0),bf(y1),bf(y2),bf(y3));
    if (full) *(ushort4*)&xf[(size_t)r*64+16*dt+4*g]=yy;
    *(ushort4*)&smem[w][m*72+16*dt+4*g]=yy;
  }
  __syncthreads();
  bf16x8 yb0=*(const bf16x8*)&smem[w][m*72+8*g];
  bf16x8 yb1=*(const bf16x8*)&smem[w][m*72+32+8*g];
  #pragma unroll
  for(int dt=0;dt<4;dt++){
    f32x4 aS=MFMA16(FS[(dt*2+1)*64+l],yb1,MFMA16(FS[(dt*2+0)*64+l],yb0,z));
    float4 sb4=*(const float4*)&sb[16*dt+4*g];
    size_t o=(size_t)r*64+16*dt+4*g;
    float4 sv=*(float4*)&skip[o];
    sv.x+=aS[0]+sb4.x; sv.y+=aS[1]+sb4.y; sv.z+=aS[2]+sb4.z; sv.w+=aS[3]+sb4.w;
    *(float4*)&skip[o]=sv;
  }
  if (full){
    #pragma unroll
    for(int dt=0;dt<4;dt++){
      f32x4 aW=MFMA16(CW0[(dt*2+1)*64+l],yb1,MFMA16(CW0[(dt*2+0)*64+l],yb0,z));
      *(ushort4*)&xw[(size_t)r*64+16*dt+4*g]=make_ushort4(bf(aW[0]),bf(aW[1]),bf(aW[2]),bf(aW[3]));
      f32x4 aH=MFMA16(CG0[(dt*2+1)*64+l],yb1,MFMA16(CG0[(dt*2+0)*64+l],yb0,z));
      *(ushort4*)&xwg[(size_t)r*64+16*dt+4*g]=make_ushort4(bf(aH[0]),bf(aH[1]),bf(aH[2]),bf(aH[3]));
    }
  }
}

// ---------------- comb1: blend in place + wA/wB epilogue ----------------
__global__ __launch_bounds__(256) void k_comb_m(
    unsigned short* __restrict__ xd, const unsigned short* __restrict__ xg,
    const unsigned short* __restrict__ xs, const float* __restrict__ ws,
    unsigned short* __restrict__ wA, unsigned short* __restrict__ wB){
  int tid=threadIdx.x, w=tid>>6, l=tid&63, m=l&15, g=l>>4;
  const bf16x8* FA=(const bf16x8*)(ws+O_WFT+FR_WFA);
  const bf16x8* GA=(const bf16x8*)(ws+O_WFT+FR_WGA);
  const bf16x8* BB=(const bf16x8*)(ws+O_WFT+FR_WBB);
  int r=blockIdx.x*64+w*16+m;
  const unsigned short* pd=xd+(size_t)r*64;
  const unsigned short* pg=xg+(size_t)r*64;
  const unsigned short* p0=xs+(size_t)r*64;
  bf16x8 d0=*(const bf16x8*)(pd+8*g), d1=*(const bf16x8*)(pd+32+8*g);
  bf16x8 g0=*(const bf16x8*)(pg+8*g), g1=*(const bf16x8*)(pg+32+8*g);
  bf16x8 s0=*(const bf16x8*)(p0+8*g), s1=*(const bf16x8*)(p0+32+8*g);
  f32x4 z; z[0]=0.f; z[1]=0.f; z[2]=0.f; z[3]=0.f;
  #pragma unroll
  for(int dt=0;dt<4;dt++){
    f32x4 a=MFMA16(FA[(dt*2+0)*64+l],d0,z);
    a=MFMA16(FA[(dt*2+1)*64+l],d1,a);
    a=MFMA16(GA[(dt*2+0)*64+l],g0,a);
    a=MFMA16(GA[(dt*2+1)*64+l],g1,a);
    a=MFMA16(BB[(dt*2+0)*64+l],s0,a);
    a=MFMA16(BB[(dt*2+1)*64+l],s1,a);
    size_t o=(size_t)r*64+16*dt+4*g;
    ushort4 dv4=*(const ushort4*)&xd[o];
    ushort4 gv4=*(const ushort4*)&xg[o];
    float V0=sigmoidf_(a[0]), V1=sigmoidf_(a[1]), V2=sigmoidf_(a[2]), V3=sigmoidf_(a[3]);
    float o0=V0*b2f(dv4.x)+(1.f-V0)*b2f(gv4.x);
    float o1=V1*b2f(dv4.y)+(1.f-V1)*b2f(gv4.y);
    float o2=V2*b2f(dv4.z)+(1.f-V2)*b2f(gv4.z);
    float o3=V3*b2f(dv4.w)+(1.f-V3)*b2f(gv4.w);
    *(ushort4*)&xd[o]=make_ushort4(bf(o0),bf(o1),bf(o2),bf(o3));
  }
  const bf16x8* CW1=(const bf16x8*)(ws+O_WFT+FR_CW1);
  const bf16x8* CG1=(const bf16x8*)(ws+O_WFT+FR_CG1);
  #pragma unroll
  for(int dt=0;dt<4;dt++){
    f32x4 a1=MFMA16(CW1[(dt*2+1)*64+l],d1,MFMA16(CW1[(dt*2+0)*64+l],d0,z));
    *(ushort4*)&wA[(size_t)r*64+16*dt+4*g]=make_ushort4(bf(a1[0]),bf(a1[1]),bf(a1[2]),bf(a1[3]));
    f32x4 a2=MFMA16(CG1[(dt*2+1)*64+l],g1,MFMA16(CG1[(dt*2+0)*64+l],g0,z));
    *(ushort4*)&wB[(size_t)r*64+16*dt+4*g]=make_ushort4(bf(a2[0]),bf(a2[1]),bf(a2[2]),bf(a2[3]));
  }
}

// ---------------- comb2 + out-proj + LN fused ----------------
// OUT1 = blend(xd2,xg2) stays in LDS; newx = LN(cat(OUT0, OUT1) @ WO.T + ob)
__global__ __launch_bounds__(256) void k_comb_out_m(
    const unsigned short* __restrict__ xd, const unsigned short* __restrict__ xg,
    const unsigned short* __restrict__ xs, const unsigned short* __restrict__ o0m,
    const float* __restrict__ ws, const float* __restrict__ ob,
    const float* __restrict__ gamma, const float* __restrict__ beta,
    unsigned short* __restrict__ xn){
  __shared__ unsigned short smem[4][16*72];
  int tid=threadIdx.x, w=tid>>6, l=tid&63, m=l&15, g=l>>4;
  const bf16x8* FA=(const bf16x8*)(ws+O_WFT+FR_WFA);
  const bf16x8* GA=(const bf16x8*)(ws+O_WFT+FR_WGA);
  const bf16x8* BB=(const bf16x8*)(ws+O_WFT+FR_WBB);
  const bf16x8* WO=(const bf16x8*)(ws+O_WFT+FR_WO);
  int r=blockIdx.x*64+w*16+m;
  const unsigned short* pd=xd+(size_t)r*64;
  const unsigned short* pg=xg+(size_t)r*64;
  const unsigned short* p0=xs+(size_t)r*64;
  bf16x8 d0=*(const bf16x8*)(pd+8*g), d1=*(const bf16x8*)(pd+32+8*g);
  bf16x8 g0=*(const bf16x8*)(pg+8*g), g1=*(const bf16x8*)(pg+32+8*g);
  bf16x8 s0=*(const bf16x8*)(p0+8*g), s1=*(const bf16x8*)(p0+32+8*g);
  f32x4 z; z[0]=0.f; z[1]=0.f; z[2]=0.f; z[3]=0.f;
  #pragma unroll
  for(int dt=0;dt<4;dt++){
    f32x4 a=MFMA16(FA[(dt*2+0)*64+l],d0,z);
    a=MFMA16(FA[(dt*2+1)*64+l],d1,a);
    a=MFMA16(GA[(dt*2+0)*64+l],g0,a);
    a=MFMA16(GA[(dt*2+1)*64+l],g1,a);
    a=MFMA16(BB[(dt*2+0)*64+l],s0,a);
    a=MFMA16(BB[(dt*2+1)*64+l],s1,a);
    size_t o=(size_t)r*64+16*dt+4*g;
    ushort4 dv4=*(const ushort4*)&xd[o];
    ushort4 gv4=*(const ushort4*)&xg[o];
    float V0=sigmoidf_(a[0]), V1=sigmoidf_(a[1]), V2=sigmoidf_(a[2]), V3=sigmoidf_(a[3]);
    float o0=V0*b2f(dv4.x)+(1.f-V0)*b2f(gv4.x);
    float o1=V1*b2f(dv4.y)+(1.f-V1)*b2f(gv4.y);
    float o2=V2*b2f(dv4.z)+(1.f-V2)*b2f(gv4.z);
    float o3=V3*b2f(dv4.w)+(1.f-V3)*b2f(gv4.w);
    *(ushort4*)&smem[w][m*72+16*dt+4*g]=make_ushort4(bf(o0),bf(o1),bf(o2),bf(o3));
  }
  __syncthreads();
  bf16x8 o1b0=*(const bf16x8*)&smem[w][m*72+8*g];
  bf16x8 o1b1=*(const bf16x8*)&smem[w][m*72+32+8*g];
  const unsigned short* a0=o0m+(size_t)r*64;
  bf16x8 b0=*(const bf16x8*)(a0+8*g), b1=*(const bf16x8*)(a0+32+8*g);
  float y[4][4]; float s=0.f;
  #pragma unroll
  for(int dt=0;dt<4;dt++){
    f32x4 a=MFMA16(WO[(dt*4+0)*64+l],b0,z);
    a=MFMA16(WO[(dt*4+1)*64+l],b1,a);
    a=MFMA16(WO[(dt*4+2)*64+l],o1b0,a);
    a=MFMA16(WO[(dt*4+3)*64+l],o1b1,a);
    float4 bb=*(const float4*)&ob[16*dt+4*g];
    y[dt][0]=a[0]+bb.x; y[dt][1]=a[1]+bb.y; y[dt][2]=a[2]+bb.z; y[dt][3]=a[3]+bb.w;
    s+=y[dt][0]+y[dt][1]+y[dt][2]+y[dt][3];
  }
  s+=__shfl_xor(s,16); s+=__shfl_xor(s,32);
  float mean=s*(1.f/64.f);
  float q=0.f;
  #pragma unroll
  for(int dt=0;dt<4;dt++){
    #pragma unroll
    for(int j=0;j<4;j++){ float e=y[dt][j]-mean; q+=e*e; }
  }
  q+=__shfl_xor(q,16); q+=__shfl_xor(q,32);
  float rstd=rsqrtf(q*(1.f/64.f)+1e-5f);
  #pragma unroll
  for(int dt=0;dt<4;dt++){
    float4 g4=*(const float4*)&gamma[16*dt+4*g];
    float4 be4=*(const float4*)&beta[16*dt+4*g];
    *(ushort4*)&xn[(size_t)r*64+16*dt+4*g]=make_ushort4(
      bf((y[dt][0]-mean)*rstd*g4.x+be4.x),
      bf((y[dt][1]-mean)*rstd*g4.y+be4.y),
      bf((y[dt][2]-mean)*rstd*g4.z+be4.z),
      bf((y[dt][3]-mean)*rstd*g4.w+be4.w));
  }
}

__global__ __launch_bounds__(256) void k_end_m(
    const float* __restrict__ skip, const float* __restrict__ ws,
    const float* __restrict__ eb, float* __restrict__ out){
  int tid=threadIdx.x, w=tid>>6, l=tid&63, m=l&15, g=l>>4;
  const bf16x8* WE=(const bf16x8*)(ws+O_WFT+FR_WE);
  int r=blockIdx.x*64+w*16+m;
  const float* sr=skip+(size_t)r*64;
  float t0[8], t1[8];
  {
    float4 a=*(const float4*)(sr+8*g), b=*(const float4*)(sr+8*g+4);
    t0[0]=fmaxf(a.x,0.f); t0[1]=fmaxf(a.y,0.f); t0[2]=fmaxf(a.z,0.f); t0[3]=fmaxf(a.w,0.f);
    t0[4]=fmaxf(b.x,0.f); t0[5]=fmaxf(b.y,0.f); t0[6]=fmaxf(b.z,0.f); t0[7]=fmaxf(b.w,0.f);
    float4 c=*(const float4*)(sr+32+8*g), d=*(const float4*)(sr+32+8*g+4);
    t1[0]=fmaxf(c.x,0.f); t1[1]=fmaxf(c.y,0.f); t1[2]=fmaxf(c.z,0.f); t1[3]=fmaxf(c.w,0.f);
    t1[4]=fmaxf(d.x,0.f); t1[5]=fmaxf(d.y,0.f); t1[6]=fmaxf(d.z,0.f); t1[7]=fmaxf(d.w,0.f);
  }
  bf16x8 s0,s1;
  #pragma unroll
  for(int i=0;i<8;i++){ s0[i]=(short)bf(t0[i]); s1[i]=(short)bf(t1[i]); }
  f32x4 z; z[0]=0.f; z[1]=0.f; z[2]=0.f; z[3]=0.f;
  int b_=r>>14, n_=(r>>6)&255, t_=r&63;
  size_t obase=((size_t)(b_*Tq+t_)*Nq+n_)*64;
  #pragma unroll
  for(int dt=0;dt<4;dt++){
    f32x4 a=MFMA16(WE[(dt*2+1)*64+l],s1,MFMA16(WE[(dt*2+0)*64+l],s0,z));
    float4 bb=*(const float4*)&eb[16*dt+4*g];
    *(float4*)&out[obase+16*dt+4*g]=make_float4(a[0]+bb.x,a[1]+bb.y,a[2]+bb.z,a[3]+bb.w);
  }
}

// ---------------- spatial pair: blocks [0,1024): An⊗inA; [1024,2048): Ag⊗inB ----------------
__global__ __launch_bounds__(256) void k_adj2(const unsigned short* __restrict__ An,
    const unsigned short* __restrict__ Ag,
    const unsigned short* __restrict__ inA, const unsigned short* __restrict__ inB,
    unsigned short* __restrict__ outA, unsigned short* __restrict__ outB){
  __shared__ unsigned short ldsT[64*264];   // 33792 B
  int half = blockIdx.x >> 10;
  int bid = blockIdx.x & 1023;
  const unsigned short* Adj = half ? Ag : An;
  int adjStride = half ? 0 : Nq*Nq;
  const unsigned short* in = half ? inB : inA;
  unsigned short* out = half ? outB : outA;
  int tid=threadIdx.x, w=tid>>6, l=tid&63, m=l&15, g=l>>4;
  int t0 = bid & 63, mc=(bid>>6)&3, b = bid>>8;
  const unsigned short* Ar = Adj + (size_t)b*adjStride + (size_t)(mc*64 + w*16 + m)*256;
  bf16x8 afr[8];
  #pragma unroll
  for (int kc=0;kc<8;kc++) afr[kc] = *(const bf16x8*)(Ar + kc*32 + g*8);
  int dq=(tid&15)*4, ng=(tid>>4)*4;
  #pragma unroll
  for (int iter=0; iter<4; ++iter){
    int n0 = iter*64 + ng;
    const unsigned short* base = in + (((size_t)b*Nq + n0)*Tq + t0)*Dq + dq;
    ushort4 v0 = *(const ushort4*)(base);
    ushort4 v1 = *(const ushort4*)(base + 4096);
    ushort4 v2 = *(const ushort4*)(base + 8192);
    ushort4 v3 = *(const ushort4*)(base + 12288);
    *(ushort4*)&ldsT[(dq+0)*264 + n0] = make_ushort4(v0.x,v1.x,v2.x,v3.x);
    *(ushort4*)&ldsT[(dq+1)*264 + n0] = make_ushort4(v0.y,v1.y,v2.y,v3.y);
    *(ushort4*)&ldsT[(dq+2)*264 + n0] = make_ushort4(v0.z,v1.z,v2.z,v3.z);
    *(ushort4*)&ldsT[(dq+3)*264 + n0] = make_ushort4(v0.w,v1.w,v2.w,v3.w);
  }
  __syncthreads();
  f32x4 z; z[0]=0.f; z[1]=0.f; z[2]=0.f; z[3]=0.f;
  f32x4 acc[4] = {z,z,z,z};
  #pragma unroll
  for (int kc=0;kc<8;kc++){
    #pragma unroll
    for (int ct=0;ct<4;ct++){
      bf16x8 bfr = *(const bf16x8*)&ldsT[(ct*16+m)*264 + kc*32 + g*8];
      acc[ct]=MFMA16(afr[kc], bfr, acc[ct]);
    }
  }
  size_t ob = (((size_t)b*Nq + mc*64 + w*16 + 4*g)*Tq + t0)*Dq;
  #pragma unroll
  for (int ct=0;ct<4;ct++){
    #pragma unroll
    for (int j=0;j<4;j++){
      out[ob + (size_t)j*Tq*Dq + ct*16 + m] = bf(acc[ct][j]);
    }
  }
}

extern "C" void kernel_launch(void* const* d_in, const int* in_sizes, int n_in,
                              void* d_out, int out_size, void* d_ws, size_t ws_size,
                              hipStream_t stream) {
  const float* X    = (const float*)d_in[0];
  const float* A    = (const float*)d_in[1];
  const float* he   = (const float*)d_in[2];
  const float* Gl   = (const float*)d_in[3];
  const float* Wq   = (const float*)d_in[4];
  const float* Wk   = (const float*)d_in[5];
  const float* nodeW= (const float*)d_in[6];
  const float* nodeB= (const float*)d_in[7];
  const float* sW   = (const float*)d_in[8];
  const float* sB   = (const float*)d_in[9];
  const float* filtW= (const float*)d_in[10];
  const float* filtB= (const float*)d_in[11];
  const float* gateW= (const float*)d_in[12];
  const float* gateB= (const float*)d_in[13];
  const float* skipW= (const float*)d_in[14];
  const float* skipB= (const float*)d_in[15];
  const float* convW= (const float*)d_in[16];
  const float* convWg=(const float*)d_in[17];
  const float* Wfuse= (const float*)d_in[18];
  const float* Wgfuse=(const float*)d_in[19];
  const float* outW = (const float*)d_in[20];
  const float* outB = (const float*)d_in[21];
  const float* gamma= (const float*)d_in[22];
  const float* beta = (const float*)d_in[23];
  const float* endW = (const float*)d_in[24];
  const float* endB = (const float*)d_in[25];
  float* ws  = (float*)d_ws;
  float* out = (float*)d_out;
  if (ws_size < (size_t)WS_FLOATS*sizeof(float)) return;

  float* Qb = ws+O_Q;  float* Kb = ws+O_K;  float* Hd = ws+O_HD;
  float* iDd= ws+O_IDD; float* iBd= ws+O_IBD;
  float* Hg = ws+O_HG; float* iDg= ws+O_IDG; float* iBg= ws+O_IBG;
  unsigned short* An = (unsigned short*)(ws+O_AN);
  unsigned short* Ag = (unsigned short*)(ws+O_AG);
  float* big= ws+O_BIG;
  // skip: fp32 slot 2; bf16 tensors: half-slots (ELEMS ushorts each)
  float* skip = big + (size_t)2*ELEMS;
  #define BFBUF(slot,h) ((unsigned short*)(big + (size_t)(slot)*ELEMS) + (size_t)(h)*ELEMS)
  unsigned short* xf  = BFBUF(0,0);
  unsigned short* xw  = BFBUF(0,1);
  unsigned short* xwg = BFBUF(1,0);
  unsigned short* xd1 = BFBUF(1,1);   // -> OUT0 after comb1
  unsigned short* xg1 = BFBUF(3,0);
  unsigned short* wA  = BFBUF(3,1);
  unsigned short* wB  = BFBUF(4,0);
  unsigned short* xd2 = BFBUF(4,1);
  unsigned short* xg2 = BFBUF(5,0);
  unsigned short* x   = BFBUF(5,1);

  k_wfrag<<<18,64,0,stream>>>(filtW,gateW,skipW,Wfuse,Wgfuse,outW,endW,convW,convWg,ws);
  k_hgeo<<<Nq,128,0,stream>>>(A,Gl,Hg,iDg);
  k_qk<<<1152,64,0,stream>>>(X,nodeW,nodeB,Wq,he,Wk,Qb,Kb);
  k_h<<<Bq*Nq,128,0,stream>>>(Qb,Kb,Hd,iDd);
  k_bdg<<<3,256,0,stream>>>(Hd,Hg,iBd,iBg);
  k_norm2<<<1280,256,0,stream>>>(Hd,iDd,iBd,Hg,iDg,iBg,An,Ag);
  k_start<<<ELEMS/1024,256,0,stream>>>(X,sW,sB,x,skip);

  for (int i=0;i<2;i++){
    k_fg_m<<<Rq/64,256,0,stream>>>(x, ws, filtB+i*64, gateB+i*64, skipB+i*64, i, 1,
                                   xf, skip, xw, xwg);
    k_adj2<<<2048,256,0,stream>>>(An, Ag, xw, xwg, xd1, xg1);
    k_comb_m<<<Rq/64,256,0,stream>>>(xd1, xg1, xf, ws, wA, wB);
    k_adj2<<<2048,256,0,stream>>>(An, Ag, wA, wB, xd2, xg2);
    k_comb_out_m<<<Rq/64,256,0,stream>>>(xd2, xg2, xf, xd1, ws, outB, gamma, beta, x);
  }
  // layer 2: only f*g + skip update feed the output (conv/out/LN of last layer is dead)
  k_fg_m<<<Rq/64,256,0,stream>>>(x, ws, filtB+2*64, gateB+2*64, skipB+2*64, 2, 0,
                                 nullptr, skip, nullptr, nullptr);
  k_end_m<<<Rq/64,256,0,stream>>>(skip, ws, endB, out);
}